// Round 1
// baseline (1141.628 us; speedup 1.0000x reference)
//
#include <hip/hip_runtime.h>
#include <math.h>

#define B_ 2
#define C_ 64
#define H_ 192
#define W_ 192
#define HW_ (H_*W_)

// ---------------------------------------------------------------------------
// Tiled direct 3x3 conv, SAME padding, NCHW. Block: 256 threads.
// Spatial tile 8 rows x 64 cols, 16 output channels per block.
// Thread (lane = col, wv = row-pair): 2 rows x 16 oc accumulators.
// EPI 0: leaky-relu epilogue. EPI 1: conv4 epilogue (tanh*10 + flow / sigmoid).
// ---------------------------------------------------------------------------
template<int CIN, int COUT, int EPI>
__global__ __launch_bounds__(256) void conv3x3_k(
    const float* __restrict__ in, const float* __restrict__ wgt,
    const float* __restrict__ bias, const float* __restrict__ flow,
    float* __restrict__ out)
{
  constexpr int NOC = (COUT + 15) / 16;
  const int tx = blockIdx.x * 64;
  const int ty = blockIdx.y * 8;
  const int b  = blockIdx.z / NOC;
  const int o0 = (blockIdx.z % NOC) * 16;
  const int tid = threadIdx.x;
  const int lane = tid & 63;
  const int wv = tid >> 6;

  __shared__ float inT[8][10][66];                 // c-chunk x (8+2 halo rows) x (64+2 halo cols)
  __shared__ __align__(16) float Wl[8][9][16];     // c-chunk x 9 taps x 16 oc

  float acc0[16], acc1[16];
  #pragma unroll
  for (int j = 0; j < 16; ++j) {
    const int oo = o0 + j;
    const float bv = (oo < COUT) ? bias[oo] : 0.f;
    acc0[j] = bv; acc1[j] = bv;
  }

  for (int c0 = 0; c0 < CIN; c0 += 8) {
    const int CC = (CIN - c0 < 8) ? (CIN - c0) : 8;

    // stage input tile (zero-padded halo)
    for (int idx = tid; idx < CC * 660; idx += 256) {
      const int c = idx / 660; int rem = idx - c * 660;
      const int r = rem / 66; const int i = rem - r * 66;
      const int y = ty + r - 1, x = tx + i - 1;
      float v = 0.f;
      if (y >= 0 && y < H_ && x >= 0 && x < W_)
        v = in[((size_t)(b * CIN + c0 + c) * H_ + y) * W_ + x];
      inT[c][r][i] = v;
    }
    // stage weights for this c-chunk
    for (int idx = tid; idx < CC * 144; idx += 256) {
      const int c = idx / 144; const int rem = idx - c * 144;
      const int k = rem >> 4; const int o = rem & 15;
      const int oo = o0 + o;
      Wl[c][k][o] = (oo < COUT) ? wgt[((size_t)oo * CIN + c0 + c) * 9 + k] : 0.f;
    }
    __syncthreads();

    for (int c = 0; c < CC; ++c) {
      float v[4][3];
      #pragma unroll
      for (int dr = 0; dr < 4; ++dr)
        #pragma unroll
        for (int di = 0; di < 3; ++di)
          v[dr][di] = inT[c][wv * 2 + dr][lane + di];

      #pragma unroll
      for (int k = 0; k < 9; ++k) {
        const float a  = v[k / 3][k % 3];
        const float bb = v[k / 3 + 1][k % 3];
        const float4* wp = (const float4*)(&Wl[c][k][0]);
        #pragma unroll
        for (int q = 0; q < 4; ++q) {
          const float4 w4 = wp[q];
          acc0[q*4+0] += a  * w4.x; acc0[q*4+1] += a  * w4.y;
          acc0[q*4+2] += a  * w4.z; acc0[q*4+3] += a  * w4.w;
          acc1[q*4+0] += bb * w4.x; acc1[q*4+1] += bb * w4.y;
          acc1[q*4+2] += bb * w4.z; acc1[q*4+3] += bb * w4.w;
        }
      }
    }
    __syncthreads();
  }

  // epilogue + store
  #pragma unroll
  for (int r = 0; r < 2; ++r) {
    const int y = ty + wv * 2 + r;
    const int xg = tx + lane;
    #pragma unroll
    for (int j = 0; j < 16; ++j) {
      const int oo = o0 + j;
      if (oo >= COUT) continue;
      float val = (r == 0) ? acc0[j] : acc1[j];
      if (EPI == 0) {
        val = (val >= 0.f) ? val : 0.1f * val;
      } else {
        if (oo < 18) {
          // offset channel: 10*tanh + flow_yx tiled (even ch -> flow[1], odd -> flow[0])
          const float f = flow[((size_t)(b * 2 + ((oo & 1) ? 0 : 1)) * H_ + y) * W_ + xg];
          val = 10.f * tanhf(val) + f;
        } else {
          val = 1.f / (1.f + expf(-val));   // sigmoid mask
        }
      }
      out[((size_t)(b * COUT + oo) * H_ + y) * W_ + xg] = val;
    }
  }
}

// ---------------------------------------------------------------------------
// weight (O=64, C=64, 3, 3) -> Wt[k][c][o]  (coalesced-in-o for deform einsum)
// ---------------------------------------------------------------------------
__global__ __launch_bounds__(256) void transpose_w(const float* __restrict__ w,
                                                   float* __restrict__ Wt)
{
  const int i = blockIdx.x * 256 + threadIdx.x;
  if (i < 64 * 64 * 9) {
    const int o = i / 576;
    const int c = (i / 9) % 64;
    const int k = i % 9;
    Wt[(k * 64 + c) * 64 + o] = w[i];
  }
}

// ---------------------------------------------------------------------------
// Deformable conv: block = 64 consecutive pixels in one row, 256 threads.
// Per k: lanes (=pixels) gather bilinear samples for 16 channels each -> LDS,
// then register-blocked matvec out[o][p] += sum_c Wt[k][c][o] * val[c][p].
// ---------------------------------------------------------------------------
__global__ __launch_bounds__(256) void deform_k(
    const float* __restrict__ x, const float* __restrict__ om,
    const float* __restrict__ Wt, const float* __restrict__ bias,
    float* __restrict__ out)
{
  const int tid = threadIdx.x;
  const int lane = tid & 63, wv = tid >> 6;
  const int g = blockIdx.x * 64;
  const int b = g / HW_;
  const int rem = g - b * HW_;
  const int h = rem / W_;
  const int w0 = rem - h * W_;

  __shared__ float offm[27][64];
  __shared__ float valk[64][64];

  for (int idx = tid; idx < 27 * 64; idx += 256) {
    const int ch = idx >> 6, p = idx & 63;
    offm[ch][p] = om[((size_t)(b * 27 + ch) * H_ + h) * W_ + w0 + p];
  }
  __syncthreads();

  float acc[16];
  #pragma unroll
  for (int j = 0; j < 16; ++j) acc[j] = bias[wv * 16 + j];

  const float* xb = x + (size_t)b * C_ * HW_;

  for (int k = 0; k < 9; ++k) {
    const int ky = k / 3, kx = k - ky * 3;
    const float dy = offm[2 * k][lane];
    const float dx = offm[2 * k + 1][lane];
    const float m  = offm[18 + k][lane];
    const float py = dy + (float)(h - 1 + ky);
    const float px = dx + (float)(w0 + lane - 1 + kx);
    const float y0f = floorf(py), x0f = floorf(px);
    const float ly = py - y0f, lx = px - x0f;
    const int y0 = (int)y0f, x0 = (int)x0f;
    const int y1 = y0 + 1, x1 = x0 + 1;
    float w00 = (1.f - ly) * (1.f - lx), w01 = (1.f - ly) * lx;
    float w10 = ly * (1.f - lx),        w11 = ly * lx;
    if (!(y0 >= 0 && y0 < H_)) { w00 = 0.f; w01 = 0.f; }
    if (!(y1 >= 0 && y1 < H_)) { w10 = 0.f; w11 = 0.f; }
    if (!(x0 >= 0 && x0 < W_)) { w00 = 0.f; w10 = 0.f; }
    if (!(x1 >= 0 && x1 < W_)) { w01 = 0.f; w11 = 0.f; }
    w00 *= m; w01 *= m; w10 *= m; w11 *= m;
    const int yc0 = min(max(y0, 0), H_ - 1), yc1 = min(max(y1, 0), H_ - 1);
    const int xc0 = min(max(x0, 0), W_ - 1), xc1 = min(max(x1, 0), W_ - 1);
    const int i00 = yc0 * W_ + xc0, i01 = yc0 * W_ + xc1;
    const int i10 = yc1 * W_ + xc0, i11 = yc1 * W_ + xc1;

    #pragma unroll
    for (int j = 0; j < 16; ++j) {
      const int c = wv + 4 * j;
      const float* xp = xb + (size_t)c * HW_;
      valk[c][lane] = w00 * xp[i00] + w01 * xp[i01] + w10 * xp[i10] + w11 * xp[i11];
    }
    __syncthreads();

    const float* wk = Wt + k * 4096 + wv * 16;
    #pragma unroll 4
    for (int c = 0; c < 64; ++c) {
      const float v = valk[c][lane];
      const float4* wp = (const float4*)(wk + c * 64);
      const float4 a0 = wp[0], a1 = wp[1], a2 = wp[2], a3 = wp[3];
      acc[0]  += v * a0.x; acc[1]  += v * a0.y; acc[2]  += v * a0.z; acc[3]  += v * a0.w;
      acc[4]  += v * a1.x; acc[5]  += v * a1.y; acc[6]  += v * a1.z; acc[7]  += v * a1.w;
      acc[8]  += v * a2.x; acc[9]  += v * a2.y; acc[10] += v * a2.z; acc[11] += v * a2.w;
      acc[12] += v * a3.x; acc[13] += v * a3.y; acc[14] += v * a3.z; acc[15] += v * a3.w;
    }
    __syncthreads();
  }

  #pragma unroll
  for (int j = 0; j < 16; ++j) {
    const int o = wv * 16 + j;
    out[((size_t)(b * C_ + o) * H_ + h) * W_ + w0 + lane] = acc[j];
  }
}

// ---------------------------------------------------------------------------
extern "C" void kernel_launch(void* const* d_in, const int* in_sizes, int n_in,
                              void* d_out, int out_size, void* d_ws, size_t ws_size,
                              hipStream_t stream) {
  const float* x         = (const float*)d_in[0];
  const float* cond_feat = (const float*)d_in[1];
  const float* flow      = (const float*)d_in[2];
  const float* w1 = (const float*)d_in[3];  const float* b1 = (const float*)d_in[4];
  const float* w2 = (const float*)d_in[5];  const float* b2 = (const float*)d_in[6];
  const float* w3 = (const float*)d_in[7];  const float* b3 = (const float*)d_in[8];
  const float* w4 = (const float*)d_in[9];  const float* b4 = (const float*)d_in[10];
  const float* wgt = (const float*)d_in[11]; const float* bias = (const float*)d_in[12];

  float* outp = (float*)d_out;
  float* ws = (float*)d_ws;
  float* bufA = ws;                                   // B*64*H*W
  float* bufC = bufA + (size_t)B_ * C_ * HW_;         // B*27*H*W (offset/mask)
  float* Wt   = bufC + (size_t)B_ * 27 * HW_;         // 9*64*64
  // d_out doubles as the conv2 ping-pong buffer (B*64*H*W, overwritten at the end)

  dim3 blk(256);
  // conv1: cond_feat(131) -> bufA, lrelu
  conv3x3_k<131, 64, 0><<<dim3(3, 24, 2 * 4), blk, 0, stream>>>(cond_feat, w1, b1, nullptr, bufA);
  // conv2: bufA -> d_out, lrelu
  conv3x3_k<64, 64, 0><<<dim3(3, 24, 2 * 4), blk, 0, stream>>>(bufA, w2, b2, nullptr, outp);
  // conv3: d_out -> bufA, lrelu
  conv3x3_k<64, 64, 0><<<dim3(3, 24, 2 * 4), blk, 0, stream>>>(outp, w3, b3, nullptr, bufA);
  // conv4: bufA -> bufC (27ch) with fused tanh/flow/sigmoid epilogue
  conv3x3_k<64, 27, 1><<<dim3(3, 24, 2 * 2), blk, 0, stream>>>(bufA, w4, b4, flow, bufC);
  // weight transpose for the deform einsum
  transpose_w<<<144, 256, 0, stream>>>(wgt, Wt);
  // deformable conv -> d_out
  deform_k<<<(B_ * HW_) / 64, 256, 0, stream>>>(x, bufC, Wt, bias, outp);
}

// Round 2
// 975.596 us; speedup vs baseline: 1.1702x; 1.1702x over previous
//
#include <hip/hip_runtime.h>
#include <math.h>

#define B_ 2
#define C_ 64
#define H_ 192
#define W_ 192
#define HW_ (H_*W_)

// ---------------------------------------------------------------------------
// Tiled direct 3x3 conv, SAME padding, NCHW. Block: 256 threads.
// Spatial tile 8 rows x 64 cols, 16 output channels per block.
// EPI 0: leaky-relu epilogue. EPI 1: conv4 epilogue (tanh*10 + flow / sigmoid).
// ---------------------------------------------------------------------------
template<int CIN, int COUT, int EPI>
__global__ __launch_bounds__(256) void conv3x3_k(
    const float* __restrict__ in, const float* __restrict__ wgt,
    const float* __restrict__ bias, const float* __restrict__ flow,
    float* __restrict__ out)
{
  constexpr int NOC = (COUT + 15) / 16;
  const int tx = blockIdx.x * 64;
  const int ty = blockIdx.y * 8;
  const int b  = blockIdx.z / NOC;
  const int o0 = (blockIdx.z % NOC) * 16;
  const int tid = threadIdx.x;
  const int lane = tid & 63;
  const int wv = tid >> 6;

  __shared__ float inT[8][10][66];
  __shared__ __align__(16) float Wl[8][9][16];

  float acc0[16], acc1[16];
  #pragma unroll
  for (int j = 0; j < 16; ++j) {
    const int oo = o0 + j;
    const float bv = (oo < COUT) ? bias[oo] : 0.f;
    acc0[j] = bv; acc1[j] = bv;
  }

  for (int c0 = 0; c0 < CIN; c0 += 8) {
    const int CC = (CIN - c0 < 8) ? (CIN - c0) : 8;

    for (int idx = tid; idx < CC * 660; idx += 256) {
      const int c = idx / 660; int rem = idx - c * 660;
      const int r = rem / 66; const int i = rem - r * 66;
      const int y = ty + r - 1, x = tx + i - 1;
      float v = 0.f;
      if (y >= 0 && y < H_ && x >= 0 && x < W_)
        v = in[((size_t)(b * CIN + c0 + c) * H_ + y) * W_ + x];
      inT[c][r][i] = v;
    }
    for (int idx = tid; idx < CC * 144; idx += 256) {
      const int c = idx / 144; const int rem = idx - c * 144;
      const int k = rem >> 4; const int o = rem & 15;
      const int oo = o0 + o;
      Wl[c][k][o] = (oo < COUT) ? wgt[((size_t)oo * CIN + c0 + c) * 9 + k] : 0.f;
    }
    __syncthreads();

    for (int c = 0; c < CC; ++c) {
      float v[4][3];
      #pragma unroll
      for (int dr = 0; dr < 4; ++dr)
        #pragma unroll
        for (int di = 0; di < 3; ++di)
          v[dr][di] = inT[c][wv * 2 + dr][lane + di];

      #pragma unroll
      for (int k = 0; k < 9; ++k) {
        const float a  = v[k / 3][k % 3];
        const float bb = v[k / 3 + 1][k % 3];
        const float4* wp = (const float4*)(&Wl[c][k][0]);
        #pragma unroll
        for (int q = 0; q < 4; ++q) {
          const float4 w4 = wp[q];
          acc0[q*4+0] += a  * w4.x; acc0[q*4+1] += a  * w4.y;
          acc0[q*4+2] += a  * w4.z; acc0[q*4+3] += a  * w4.w;
          acc1[q*4+0] += bb * w4.x; acc1[q*4+1] += bb * w4.y;
          acc1[q*4+2] += bb * w4.z; acc1[q*4+3] += bb * w4.w;
        }
      }
    }
    __syncthreads();
  }

  #pragma unroll
  for (int r = 0; r < 2; ++r) {
    const int y = ty + wv * 2 + r;
    const int xg = tx + lane;
    #pragma unroll
    for (int j = 0; j < 16; ++j) {
      const int oo = o0 + j;
      if (oo >= COUT) continue;
      float val = (r == 0) ? acc0[j] : acc1[j];
      if (EPI == 0) {
        val = (val >= 0.f) ? val : 0.1f * val;
      } else {
        if (oo < 18) {
          const float f = flow[((size_t)(b * 2 + ((oo & 1) ? 0 : 1)) * H_ + y) * W_ + xg];
          val = 10.f * tanhf(val) + f;
        } else {
          val = 1.f / (1.f + expf(-val));
        }
      }
      out[((size_t)(b * COUT + oo) * H_ + y) * W_ + xg] = val;
    }
  }
}

// ---------------------------------------------------------------------------
// weight (O=64, C=64, 3, 3) -> Wt[k][c][o]
// ---------------------------------------------------------------------------
__global__ __launch_bounds__(256) void transpose_w(const float* __restrict__ w,
                                                   float* __restrict__ Wt)
{
  const int i = blockIdx.x * 256 + threadIdx.x;
  if (i < 64 * 64 * 9) {
    const int o = i / 576;
    const int c = (i / 9) % 64;
    const int k = i % 9;
    Wt[(k * 64 + c) * 64 + o] = w[i];
  }
}

// ---------------------------------------------------------------------------
// x NCHW -> NHWC: xT[b][p][c], p = h*W+w. Block: 64 pixels, 256 threads.
// ---------------------------------------------------------------------------
__global__ __launch_bounds__(256) void transpose_x(const float* __restrict__ x,
                                                   float* __restrict__ xT)
{
  const int tid = threadIdx.x;
  const int lane = tid & 63, wv = tid >> 6;
  const int blocksPerB = HW_ / 64;   // 576
  const int b = blockIdx.x / blocksPerB;
  const int p0 = (blockIdx.x % blocksPerB) * 64;

  __shared__ float t[64][65];
  const float* xb = x + (size_t)b * C_ * HW_;
  #pragma unroll
  for (int j = 0; j < 16; ++j) {
    const int c = wv * 16 + j;
    t[c][lane] = xb[(size_t)c * HW_ + p0 + lane];
  }
  __syncthreads();
  float* xo = xT + ((size_t)b * HW_ + p0) * 64;
  const int c4 = (tid & 15) * 4;
  const int pb = tid >> 4;
  #pragma unroll
  for (int pp = 0; pp < 4; ++pp) {
    const int p = pb + 16 * pp;
    float4 v = { t[c4][p], t[c4 + 1][p], t[c4 + 2][p], t[c4 + 3][p] };
    *(float4*)(xo + (size_t)p * 64 + c4) = v;
  }
}

// ---------------------------------------------------------------------------
// Deformable conv, NHWC gather. Block = 64 pixels in one row, 256 threads.
// Phase 1: precompute corner idx/weights for all 9 taps into LDS.
// Phase 2 per tap: coalesced float4 bilinear gather -> valk[c][p] in LDS,
//                  then register-blocked matvec (16 oc per thread).
// ---------------------------------------------------------------------------
__global__ __launch_bounds__(256) void deform_k(
    const float* __restrict__ xT, const float* __restrict__ om,
    const float* __restrict__ Wt, const float* __restrict__ bias,
    float* __restrict__ out)
{
  const int tid = threadIdx.x;
  const int lane = tid & 63, wv = tid >> 6;
  const int blocksPerB = HW_ / 64;
  const int b = blockIdx.x / blocksPerB;
  const int rem = blockIdx.x % blocksPerB;
  const int h = (rem * 64) / W_;
  const int w0 = (rem * 64) % W_;

  __shared__ int   ci[4][9][64];
  __shared__ float cw[4][9][64];
  __shared__ float valk[64][65];

  // phase 1: corner indices & weights (mask folded in) for all 9 taps
  for (int idx = tid; idx < 9 * 64; idx += 256) {
    const int k = idx >> 6, p = idx & 63;
    const size_t base = (size_t)b * 27 * HW_ + (size_t)h * W_ + w0 + p;
    const float dy = om[base + (size_t)(2 * k) * HW_];
    const float dx = om[base + (size_t)(2 * k + 1) * HW_];
    const float m  = om[base + (size_t)(18 + k) * HW_];
    const int ky = k / 3, kx = k - ky * 3;
    const float py = dy + (float)(h - 1 + ky);
    const float px = dx + (float)(w0 + p - 1 + kx);
    const float y0f = floorf(py), x0f = floorf(px);
    const float ly = py - y0f, lx = px - x0f;
    const int y0 = (int)y0f, x0 = (int)x0f;
    const int y1 = y0 + 1, x1 = x0 + 1;
    float w00 = (1.f - ly) * (1.f - lx), w01 = (1.f - ly) * lx;
    float w10 = ly * (1.f - lx),        w11 = ly * lx;
    if (!(y0 >= 0 && y0 < H_)) { w00 = 0.f; w01 = 0.f; }
    if (!(y1 >= 0 && y1 < H_)) { w10 = 0.f; w11 = 0.f; }
    if (!(x0 >= 0 && x0 < W_)) { w00 = 0.f; w10 = 0.f; }
    if (!(x1 >= 0 && x1 < W_)) { w01 = 0.f; w11 = 0.f; }
    const int yc0 = min(max(y0, 0), H_ - 1), yc1 = min(max(y1, 0), H_ - 1);
    const int xc0 = min(max(x0, 0), W_ - 1), xc1 = min(max(x1, 0), W_ - 1);
    ci[0][k][p] = yc0 * W_ + xc0;  cw[0][k][p] = m * w00;
    ci[1][k][p] = yc0 * W_ + xc1;  cw[1][k][p] = m * w01;
    ci[2][k][p] = yc1 * W_ + xc0;  cw[2][k][p] = m * w10;
    ci[3][k][p] = yc1 * W_ + xc1;  cw[3][k][p] = m * w11;
  }

  float acc[16];
  #pragma unroll
  for (int j = 0; j < 16; ++j) acc[j] = bias[wv * 16 + j];

  const float* xb = xT + (size_t)b * HW_ * 64;
  const int c4 = (tid & 15) * 4;
  const int pb = tid >> 4;

  __syncthreads();

  for (int k = 0; k < 9; ++k) {
    // phase 2a: coalesced bilinear gather -> valk
    #pragma unroll
    for (int pp = 0; pp < 4; ++pp) {
      const int p = pb + 16 * pp;
      const int i00 = ci[0][k][p], i01 = ci[1][k][p];
      const int i10 = ci[2][k][p], i11 = ci[3][k][p];
      const float q00 = cw[0][k][p], q01 = cw[1][k][p];
      const float q10 = cw[2][k][p], q11 = cw[3][k][p];
      const float4 a  = *(const float4*)(xb + (size_t)i00 * 64 + c4);
      const float4 bb = *(const float4*)(xb + (size_t)i01 * 64 + c4);
      const float4 cc = *(const float4*)(xb + (size_t)i10 * 64 + c4);
      const float4 dd = *(const float4*)(xb + (size_t)i11 * 64 + c4);
      valk[c4 + 0][p] = q00 * a.x + q01 * bb.x + q10 * cc.x + q11 * dd.x;
      valk[c4 + 1][p] = q00 * a.y + q01 * bb.y + q10 * cc.y + q11 * dd.y;
      valk[c4 + 2][p] = q00 * a.z + q01 * bb.z + q10 * cc.z + q11 * dd.z;
      valk[c4 + 3][p] = q00 * a.w + q01 * bb.w + q10 * cc.w + q11 * dd.w;
    }
    __syncthreads();

    // phase 2b: matvec out[o][p] += sum_c Wt[k][c][o] * valk[c][p]
    const float* wk = Wt + k * 4096 + wv * 16;
    #pragma unroll 4
    for (int c = 0; c < 64; ++c) {
      const float v = valk[c][lane];
      const float4* wp = (const float4*)(wk + c * 64);
      const float4 a0 = wp[0], a1 = wp[1], a2 = wp[2], a3 = wp[3];
      acc[0]  += v * a0.x; acc[1]  += v * a0.y; acc[2]  += v * a0.z; acc[3]  += v * a0.w;
      acc[4]  += v * a1.x; acc[5]  += v * a1.y; acc[6]  += v * a1.z; acc[7]  += v * a1.w;
      acc[8]  += v * a2.x; acc[9]  += v * a2.y; acc[10] += v * a2.z; acc[11] += v * a2.w;
      acc[12] += v * a3.x; acc[13] += v * a3.y; acc[14] += v * a3.z; acc[15] += v * a3.w;
    }
    __syncthreads();
  }

  #pragma unroll
  for (int j = 0; j < 16; ++j) {
    const int o = wv * 16 + j;
    out[((size_t)(b * C_ + o) * HW_) + (size_t)h * W_ + w0 + lane] = acc[j];
  }
}

// ---------------------------------------------------------------------------
extern "C" void kernel_launch(void* const* d_in, const int* in_sizes, int n_in,
                              void* d_out, int out_size, void* d_ws, size_t ws_size,
                              hipStream_t stream) {
  const float* x         = (const float*)d_in[0];
  const float* cond_feat = (const float*)d_in[1];
  const float* flow      = (const float*)d_in[2];
  const float* w1 = (const float*)d_in[3];  const float* b1 = (const float*)d_in[4];
  const float* w2 = (const float*)d_in[5];  const float* b2 = (const float*)d_in[6];
  const float* w3 = (const float*)d_in[7];  const float* b3 = (const float*)d_in[8];
  const float* w4 = (const float*)d_in[9];  const float* b4 = (const float*)d_in[10];
  const float* wgt = (const float*)d_in[11]; const float* bias = (const float*)d_in[12];

  float* outp = (float*)d_out;
  float* ws = (float*)d_ws;
  float* bufA = ws;                                   // B*64*H*W (conv ping; later xT)
  float* bufC = bufA + (size_t)B_ * C_ * HW_;         // B*27*H*W (offset/mask)
  float* Wt   = bufC + (size_t)B_ * 27 * HW_;         // 9*64*64

  dim3 blk(256);
  conv3x3_k<131, 64, 0><<<dim3(3, 24, 2 * 4), blk, 0, stream>>>(cond_feat, w1, b1, nullptr, bufA);
  conv3x3_k<64, 64, 0><<<dim3(3, 24, 2 * 4), blk, 0, stream>>>(bufA, w2, b2, nullptr, outp);
  conv3x3_k<64, 64, 0><<<dim3(3, 24, 2 * 4), blk, 0, stream>>>(outp, w3, b3, nullptr, bufA);
  conv3x3_k<64, 27, 1><<<dim3(3, 24, 2 * 2), blk, 0, stream>>>(bufA, w4, b4, flow, bufC);
  transpose_w<<<144, 256, 0, stream>>>(wgt, Wt);
  // bufA is dead after conv4 -> reuse as NHWC x
  transpose_x<<<(B_ * HW_) / 64, 256, 0, stream>>>(x, bufA);
  deform_k<<<(B_ * HW_) / 64, 256, 0, stream>>>(bufA, bufC, Wt, bias, outp);
}

// Round 3
// 651.206 us; speedup vs baseline: 1.7531x; 1.4981x over previous
//
#include <hip/hip_runtime.h>
#include <math.h>

#define B_ 2
#define C_ 64
#define H_ 192
#define W_ 192
#define HW_ (H_*W_)

typedef __attribute__((ext_vector_type(8))) short  bf16x8;
typedef __attribute__((ext_vector_type(4))) float  f32x4;
typedef __attribute__((ext_vector_type(4))) unsigned u32x4;

__device__ inline unsigned short f2bf(float f) {           // RNE fp32->bf16
  unsigned u = __float_as_uint(f);
  return (unsigned short)((u + 0x7fffu + ((u >> 16) & 1u)) >> 16);
}
__device__ inline float bflo(unsigned u) { return __uint_as_float(u << 16); }
__device__ inline float bfhi(unsigned u) { return __uint_as_float(u & 0xffff0000u); }
__device__ inline unsigned pkbf(float a, float b) {
  unsigned ua = __float_as_uint(a), ub = __float_as_uint(b);
  ua = (ua + 0x7fffu + ((ua >> 16) & 1u)) >> 16;
  ub = (ub + 0x7fffu + ((ub >> 16) & 1u)) >> 16;
  return ua | (ub << 16);
}

// ---------------------------------------------------------------------------
// Tiled direct 3x3 conv, SAME padding, NCHW fp32 (unchanged from round 2).
// ---------------------------------------------------------------------------
template<int CIN, int COUT, int EPI>
__global__ __launch_bounds__(256) void conv3x3_k(
    const float* __restrict__ in, const float* __restrict__ wgt,
    const float* __restrict__ bias, const float* __restrict__ flow,
    float* __restrict__ out)
{
  constexpr int NOC = (COUT + 15) / 16;
  const int tx = blockIdx.x * 64;
  const int ty = blockIdx.y * 8;
  const int b  = blockIdx.z / NOC;
  const int o0 = (blockIdx.z % NOC) * 16;
  const int tid = threadIdx.x;
  const int lane = tid & 63;
  const int wv = tid >> 6;

  __shared__ float inT[8][10][66];
  __shared__ __align__(16) float Wl[8][9][16];

  float acc0[16], acc1[16];
  #pragma unroll
  for (int j = 0; j < 16; ++j) {
    const int oo = o0 + j;
    const float bv = (oo < COUT) ? bias[oo] : 0.f;
    acc0[j] = bv; acc1[j] = bv;
  }

  for (int c0 = 0; c0 < CIN; c0 += 8) {
    const int CC = (CIN - c0 < 8) ? (CIN - c0) : 8;

    for (int idx = tid; idx < CC * 660; idx += 256) {
      const int c = idx / 660; int rem = idx - c * 660;
      const int r = rem / 66; const int i = rem - r * 66;
      const int y = ty + r - 1, x = tx + i - 1;
      float v = 0.f;
      if (y >= 0 && y < H_ && x >= 0 && x < W_)
        v = in[((size_t)(b * CIN + c0 + c) * H_ + y) * W_ + x];
      inT[c][r][i] = v;
    }
    for (int idx = tid; idx < CC * 144; idx += 256) {
      const int c = idx / 144; const int rem = idx - c * 144;
      const int k = rem >> 4; const int o = rem & 15;
      const int oo = o0 + o;
      Wl[c][k][o] = (oo < COUT) ? wgt[((size_t)oo * CIN + c0 + c) * 9 + k] : 0.f;
    }
    __syncthreads();

    for (int c = 0; c < CC; ++c) {
      float v[4][3];
      #pragma unroll
      for (int dr = 0; dr < 4; ++dr)
        #pragma unroll
        for (int di = 0; di < 3; ++di)
          v[dr][di] = inT[c][wv * 2 + dr][lane + di];

      #pragma unroll
      for (int k = 0; k < 9; ++k) {
        const float a  = v[k / 3][k % 3];
        const float bb = v[k / 3 + 1][k % 3];
        const float4* wp = (const float4*)(&Wl[c][k][0]);
        #pragma unroll
        for (int q = 0; q < 4; ++q) {
          const float4 w4 = wp[q];
          acc0[q*4+0] += a  * w4.x; acc0[q*4+1] += a  * w4.y;
          acc0[q*4+2] += a  * w4.z; acc0[q*4+3] += a  * w4.w;
          acc1[q*4+0] += bb * w4.x; acc1[q*4+1] += bb * w4.y;
          acc1[q*4+2] += bb * w4.z; acc1[q*4+3] += bb * w4.w;
        }
      }
    }
    __syncthreads();
  }

  #pragma unroll
  for (int r = 0; r < 2; ++r) {
    const int y = ty + wv * 2 + r;
    const int xg = tx + lane;
    #pragma unroll
    for (int j = 0; j < 16; ++j) {
      const int oo = o0 + j;
      if (oo >= COUT) continue;
      float val = (r == 0) ? acc0[j] : acc1[j];
      if (EPI == 0) {
        val = (val >= 0.f) ? val : 0.1f * val;
      } else {
        if (oo < 18) {
          const float f = flow[((size_t)(b * 2 + ((oo & 1) ? 0 : 1)) * H_ + y) * W_ + xg];
          val = 10.f * tanhf(val) + f;
        } else {
          val = 1.f / (1.f + expf(-val));
        }
      }
      out[((size_t)(b * COUT + oo) * H_ + y) * W_ + xg] = val;
    }
  }
}

// ---------------------------------------------------------------------------
// weight (O=64,C=64,3,3) fp32 -> W2[k][o][c] bf16 (c contiguous for A-frags)
// ---------------------------------------------------------------------------
__global__ __launch_bounds__(256) void prep_w2(const float* __restrict__ w,
                                               unsigned short* __restrict__ W2)
{
  const int i = blockIdx.x * 256 + threadIdx.x;
  if (i < 64 * 64 * 9) {
    const int o = i / 576;
    const int rem = i % 576;
    const int c = rem / 9;
    const int k = rem % 9;
    W2[((size_t)k * 64 + o) * 64 + c] = f2bf(w[i]);
  }
}

// ---------------------------------------------------------------------------
// x NCHW fp32 -> NHWC bf16: xTb[b][p][c]. Block: 64 pixels, 256 threads.
// ---------------------------------------------------------------------------
__global__ __launch_bounds__(256) void transpose_x(const float* __restrict__ x,
                                                   unsigned short* __restrict__ xTb)
{
  const int tid = threadIdx.x;
  const int lane = tid & 63, wv = tid >> 6;
  const int blocksPerB = HW_ / 64;
  const int b = blockIdx.x / blocksPerB;
  const int p0 = (blockIdx.x % blocksPerB) * 64;

  __shared__ float t[64][65];
  const float* xb = x + (size_t)b * C_ * HW_;
  #pragma unroll
  for (int j = 0; j < 16; ++j) {
    const int c = wv * 16 + j;
    t[c][lane] = xb[(size_t)c * HW_ + p0 + lane];
  }
  __syncthreads();
  unsigned short* xo = xTb + ((size_t)b * HW_ + p0) * 64;
  const int c4 = (tid & 15) * 4;
  const int pb = tid >> 4;
  #pragma unroll
  for (int pp = 0; pp < 4; ++pp) {
    const int p = pb + 16 * pp;
    ushort4 v = { f2bf(t[c4][p]), f2bf(t[c4+1][p]), f2bf(t[c4+2][p]), f2bf(t[c4+3][p]) };
    *(ushort4*)(xo + (size_t)p * 64 + c4) = v;
  }
}

// ---------------------------------------------------------------------------
// Deformable conv, bf16 MFMA. Block = 64 px in one row, 256 threads (4 waves).
// Per tap: threads gather (p, 8-ch group) bilinear samples -> bf16 valk[p][c]
// (XOR-swizzled 16B slots), then wave wv does 8x mfma_16x16x32_bf16 for its
// 16-oc strip. A = W2[k][o][c] (global/L1), B = valk (ds_read_b128).
// ---------------------------------------------------------------------------
__global__ __launch_bounds__(256) void deform_k(
    const unsigned short* __restrict__ xTb, const float* __restrict__ om,
    const unsigned short* __restrict__ W2, const float* __restrict__ bias,
    float* __restrict__ out)
{
  const int tid = threadIdx.x;
  const int lane = tid & 63, wv = tid >> 6;
  const int g = lane >> 4;           // 0..3
  const int l16 = lane & 15;
  const int blocksPerB = HW_ / 64;
  const int b = blockIdx.x / blocksPerB;
  const int rem = blockIdx.x % blocksPerB;
  const int h = (rem * 64) / W_;
  const int w0 = (rem * 64) % W_;

  __shared__ int   ci[4][9][64];
  __shared__ float cw[4][9][64];
  __shared__ __align__(16) unsigned short valk[64 * 64];   // [p][c-swizzled]

  // phase 1: corner indices & weights (mask folded) for all 9 taps
  for (int idx = tid; idx < 9 * 64; idx += 256) {
    const int k = idx >> 6, p = idx & 63;
    const size_t base = (size_t)b * 27 * HW_ + (size_t)h * W_ + w0 + p;
    const float dy = om[base + (size_t)(2 * k) * HW_];
    const float dx = om[base + (size_t)(2 * k + 1) * HW_];
    const float m  = om[base + (size_t)(18 + k) * HW_];
    const int ky = k / 3, kx = k - ky * 3;
    const float py = dy + (float)(h - 1 + ky);
    const float px = dx + (float)(w0 + p - 1 + kx);
    const float y0f = floorf(py), x0f = floorf(px);
    const float ly = py - y0f, lx = px - x0f;
    const int y0 = (int)y0f, x0 = (int)x0f;
    const int y1 = y0 + 1, x1 = x0 + 1;
    float w00 = (1.f - ly) * (1.f - lx), w01 = (1.f - ly) * lx;
    float w10 = ly * (1.f - lx),        w11 = ly * lx;
    if (!(y0 >= 0 && y0 < H_)) { w00 = 0.f; w01 = 0.f; }
    if (!(y1 >= 0 && y1 < H_)) { w10 = 0.f; w11 = 0.f; }
    if (!(x0 >= 0 && x0 < W_)) { w00 = 0.f; w10 = 0.f; }
    if (!(x1 >= 0 && x1 < W_)) { w01 = 0.f; w11 = 0.f; }
    const int yc0 = min(max(y0, 0), H_ - 1), yc1 = min(max(y1, 0), H_ - 1);
    const int xc0 = min(max(x0, 0), W_ - 1), xc1 = min(max(x1, 0), W_ - 1);
    ci[0][k][p] = yc0 * W_ + xc0;  cw[0][k][p] = m * w00;
    ci[1][k][p] = yc0 * W_ + xc1;  cw[1][k][p] = m * w01;
    ci[2][k][p] = yc1 * W_ + xc0;  cw[2][k][p] = m * w10;
    ci[3][k][p] = yc1 * W_ + xc1;  cw[3][k][p] = m * w11;
  }

  f32x4 acc[4];
  {
    float br[4];
    #pragma unroll
    for (int r = 0; r < 4; ++r) br[r] = bias[wv * 16 + g * 4 + r];
    #pragma unroll
    for (int n = 0; n < 4; ++n) { acc[n][0]=br[0]; acc[n][1]=br[1]; acc[n][2]=br[2]; acc[n][3]=br[3]; }
  }

  const unsigned short* xb = xTb + (size_t)b * HW_ * 64;
  __syncthreads();

  for (int k = 0; k < 9; ++k) {
    // gather: 512 items (p, cg) -> valk
    #pragma unroll
    for (int i = 0; i < 2; ++i) {
      const int it = tid + (i << 8);
      const int cg = it & 7, p = it >> 3;
      const int i00 = ci[0][k][p], i01 = ci[1][k][p];
      const int i10 = ci[2][k][p], i11 = ci[3][k][p];
      const float q00 = cw[0][k][p], q01 = cw[1][k][p];
      const float q10 = cw[2][k][p], q11 = cw[3][k][p];
      const u32x4 va = *(const u32x4*)(xb + ((size_t)i00 * 64 + cg * 8));
      const u32x4 vb = *(const u32x4*)(xb + ((size_t)i01 * 64 + cg * 8));
      const u32x4 vc = *(const u32x4*)(xb + ((size_t)i10 * 64 + cg * 8));
      const u32x4 vd = *(const u32x4*)(xb + ((size_t)i11 * 64 + cg * 8));
      u32x4 res;
      #pragma unroll
      for (int j = 0; j < 4; ++j) {
        const float lo = q00*bflo(va[j]) + q01*bflo(vb[j]) + q10*bflo(vc[j]) + q11*bflo(vd[j]);
        const float hi = q00*bfhi(va[j]) + q01*bfhi(vb[j]) + q10*bfhi(vc[j]) + q11*bfhi(vd[j]);
        res[j] = pkbf(lo, hi);
      }
      *(u32x4*)&valk[(p << 6) + ((cg ^ (p & 7)) << 3)] = res;
    }

    // A-fragments (weights) — independent of valk, issue before barrier
    const unsigned short* w2t = W2 + ((size_t)k * 64 + wv * 16 + l16) * 64 + g * 8;
    const bf16x8 a0 = *(const bf16x8*)(w2t);
    const bf16x8 a1 = *(const bf16x8*)(w2t + 32);

    __syncthreads();   // valk ready

    #pragma unroll
    for (int n = 0; n < 4; ++n) {
      const int p = n * 16 + l16;
      const bf16x8 b0 = *(const bf16x8*)&valk[(p << 6) + (((g    ) ^ (p & 7)) << 3)];
      const bf16x8 b1 = *(const bf16x8*)&valk[(p << 6) + (((g + 4) ^ (p & 7)) << 3)];
      acc[n] = __builtin_amdgcn_mfma_f32_16x16x32_bf16(a0, b0, acc[n], 0, 0, 0);
      acc[n] = __builtin_amdgcn_mfma_f32_16x16x32_bf16(a1, b1, acc[n], 0, 0, 0);
    }
    __syncthreads();   // protect valk before next tap's writes
  }

  // epilogue: D[row=oc_local][col=px_local], row=(lane>>4)*4+r, col=lane&15
  #pragma unroll
  for (int n = 0; n < 4; ++n) {
    #pragma unroll
    for (int r = 0; r < 4; ++r) {
      const int oc = wv * 16 + g * 4 + r;
      out[((size_t)(b * C_ + oc) * HW_) + (size_t)h * W_ + w0 + n * 16 + l16] = acc[n][r];
    }
  }
}

// ---------------------------------------------------------------------------
extern "C" void kernel_launch(void* const* d_in, const int* in_sizes, int n_in,
                              void* d_out, int out_size, void* d_ws, size_t ws_size,
                              hipStream_t stream) {
  const float* x         = (const float*)d_in[0];
  const float* cond_feat = (const float*)d_in[1];
  const float* flow      = (const float*)d_in[2];
  const float* w1 = (const float*)d_in[3];  const float* b1 = (const float*)d_in[4];
  const float* w2 = (const float*)d_in[5];  const float* b2 = (const float*)d_in[6];
  const float* w3 = (const float*)d_in[7];  const float* b3 = (const float*)d_in[8];
  const float* w4 = (const float*)d_in[9];  const float* b4 = (const float*)d_in[10];
  const float* wgt = (const float*)d_in[11]; const float* bias = (const float*)d_in[12];

  float* outp = (float*)d_out;
  float* ws = (float*)d_ws;
  float* bufA = ws;                                   // B*64*H*W fp32 (conv ping; later bf16 xTb)
  float* bufC = bufA + (size_t)B_ * C_ * HW_;         // B*27*H*W fp32 (offset/mask)
  unsigned short* W2 = (unsigned short*)(bufC + (size_t)B_ * 27 * HW_);  // 9*64*64 bf16
  unsigned short* xTb = (unsigned short*)bufA;        // B*HW*64 bf16 (9.4 MB <= 18.9 MB)

  dim3 blk(256);
  conv3x3_k<131, 64, 0><<<dim3(3, 24, 2 * 4), blk, 0, stream>>>(cond_feat, w1, b1, nullptr, bufA);
  conv3x3_k<64, 64, 0><<<dim3(3, 24, 2 * 4), blk, 0, stream>>>(bufA, w2, b2, nullptr, outp);
  conv3x3_k<64, 64, 0><<<dim3(3, 24, 2 * 4), blk, 0, stream>>>(outp, w3, b3, nullptr, bufA);
  conv3x3_k<64, 27, 1><<<dim3(3, 24, 2 * 2), blk, 0, stream>>>(bufA, w4, b4, flow, bufC);
  prep_w2<<<144, 256, 0, stream>>>(wgt, W2);
  // bufA (fp32 conv ping) is dead after conv4 -> reuse region as bf16 NHWC x
  transpose_x<<<(B_ * HW_) / 64, 256, 0, stream>>>(x, xTb);
  deform_k<<<(B_ * HW_) / 64, 256, 0, stream>>>(xTb, bufC, W2, bias, outp);
}

// Round 4
// 257.609 us; speedup vs baseline: 4.4316x; 2.5279x over previous
//
#include <hip/hip_runtime.h>
#include <math.h>

#define B_ 2
#define C_ 64
#define H_ 192
#define W_ 192
#define HW_ (H_*W_)
#define PR_ 194      // padded row length (W+2)

typedef __attribute__((ext_vector_type(8))) short    bf16x8;
typedef __attribute__((ext_vector_type(4))) float    f32x4;
typedef __attribute__((ext_vector_type(4))) unsigned u32x4;

__device__ inline unsigned short f2bf(float f) {           // RNE fp32->bf16
  unsigned u = __float_as_uint(f);
  return (unsigned short)((u + 0x7fffu + ((u >> 16) & 1u)) >> 16);
}
__device__ inline float bf2f(unsigned short h) { return __uint_as_float((unsigned)h << 16); }
__device__ inline float bflo(unsigned u) { return __uint_as_float(u << 16); }
__device__ inline float bfhi(unsigned u) { return __uint_as_float(u & 0xffff0000u); }
__device__ inline unsigned pkbf(float a, float b) {
  unsigned ua = __float_as_uint(a), ub = __float_as_uint(b);
  ua = (ua + 0x7fffu + ((ua >> 16) & 1u)) >> 16;
  ub = (ub + 0x7fffu + ((ub >> 16) & 1u)) >> 16;
  return ua | (ub << 16);
}

// ---------------------------------------------------------------------------
// conv weight OIHW fp32 -> [k][o][c] hi/lo bf16 planes (zero-padded o,c)
// ---------------------------------------------------------------------------
template<int O, int CIN, int OPAD, int CPAD>
__global__ __launch_bounds__(256) void prep_cw(const float* __restrict__ w,
                                               unsigned short* __restrict__ WH,
                                               unsigned short* __restrict__ WL)
{
  const int i = blockIdx.x * 256 + threadIdx.x;
  if (i >= 9 * OPAD * CPAD) return;
  const int k = i / (OPAD * CPAD);
  const int r = i % (OPAD * CPAD);
  const int o = r / CPAD;
  const int c = r % CPAD;
  float v = (o < O && c < CIN) ? w[((size_t)o * CIN + c) * 9 + k] : 0.f;
  const unsigned short h = f2bf(v);
  WH[i] = h;
  WL[i] = f2bf(v - bf2f(h));
}

// ---------------------------------------------------------------------------
// cond_feat fp32 NCHW (131ch) -> NHWC-padded hi/lo bf16 [b][194][194][160]
// one block per (b, padded row)
// ---------------------------------------------------------------------------
__global__ __launch_bounds__(256) void transpose_cond(const float* __restrict__ cond,
                                                      unsigned short* __restrict__ cH,
                                                      unsigned short* __restrict__ cL)
{
  const int tid = threadIdx.x;
  const int b  = blockIdx.x / PR_;
  const int yp = blockIdx.x % PR_;
  const size_t ob = ((size_t)(b * PR_ + yp) * PR_) * 160;

  if (yp == 0 || yp == PR_ - 1) {                 // halo row: all zeros
    for (int idx = tid; idx < PR_ * 160 / 8; idx += 256) {
      u32x4 z = {0, 0, 0, 0};
      *(u32x4*)(cH + ob + (size_t)idx * 8) = z;
      *(u32x4*)(cL + ob + (size_t)idx * 8) = z;
    }
    return;
  }
  const int y = yp - 1;
  __shared__ float t[32][PR_];

  for (int cc = 0; cc < 5; ++cc) {
    __syncthreads();
    for (int idx = tid; idx < 32 * 192; idx += 256) {
      const int ci = idx / 192, px = idx % 192;
      const int c = cc * 32 + ci;
      t[ci][px + 1] = (c < 131) ? cond[(((size_t)b * 131 + c) * H_ + y) * W_ + px] : 0.f;
    }
    if (tid < 32) { t[tid][0] = 0.f; t[tid][PR_ - 1] = 0.f; }
    __syncthreads();
    if (tid < PR_) {
      const int xp = tid;
      const size_t o2 = ob + (size_t)xp * 160 + cc * 32;
      #pragma unroll
      for (int j = 0; j < 4; ++j) {
        u32x4 vh, vl;
        #pragma unroll
        for (int q = 0; q < 4; ++q) {
          const int c0 = j * 8 + q * 2;
          const float va = t[c0][xp], vb = t[c0 + 1][xp];
          const unsigned short ha = f2bf(va), hb = f2bf(vb);
          vh[q] = (unsigned)ha | ((unsigned)hb << 16);
          const unsigned short la = f2bf(va - bf2f(ha)), lb = f2bf(vb - bf2f(hb));
          vl[q] = (unsigned)la | ((unsigned)lb << 16);
        }
        *(u32x4*)(cH + o2 + j * 8) = vh;
        *(u32x4*)(cL + o2 + j * 8) = vl;
      }
    }
  }
}

// ---------------------------------------------------------------------------
// zero halo (rows 0/193, cols 0/193) of a 64-ch padded NHWC hi/lo pair
// ---------------------------------------------------------------------------
__global__ __launch_bounds__(256) void halo_zero(unsigned short* __restrict__ H,
                                                 unsigned short* __restrict__ L)
{
  const int idx = blockIdx.x * 256 + threadIdx.x;
  if (idx >= B_ * PR_ * PR_) return;
  const int r  = idx % (PR_ * PR_);
  const int yp = r / PR_, xp = r % PR_;
  if (yp == 0 || yp == PR_ - 1 || xp == 0 || xp == PR_ - 1) {
    u32x4 z = {0, 0, 0, 0};
    const size_t base = (size_t)idx * 64;
    #pragma unroll
    for (int j = 0; j < 8; ++j) {
      *(u32x4*)(H + base + j * 8) = z;
      *(u32x4*)(L + base + j * 8) = z;
    }
  }
}

// ---------------------------------------------------------------------------
// MFMA 3x3 conv on NHWC-padded hi/lo bf16. Tile 64px x (NW*16) oc.
// 3-term hi/lo MFMA: W_h*x_h + W_l*x_h + W_h*x_l (fp32 acc).
// EPI 0: lrelu -> hi/lo split -> padded NHWC store (via LDS transpose).
// EPI 1: conv4 offsets/mask epilogue -> fp32 NCHW om (27 ch).
// ---------------------------------------------------------------------------
template<int NCC, int NW, int EPI, int CPADI>
__global__ __launch_bounds__(NW * 64) void conv_mfma(
    const unsigned short* __restrict__ inH, const unsigned short* __restrict__ inL,
    const unsigned short* __restrict__ WH, const unsigned short* __restrict__ WL,
    const float* __restrict__ bias, const float* __restrict__ flow,
    unsigned short* __restrict__ outH, unsigned short* __restrict__ outL,
    float* __restrict__ om)
{
  constexpr int OPAD = NW * 16;
  const int tid = threadIdx.x;
  const int lane = tid & 63, wv = tid >> 6;
  const int g = lane >> 4, l16 = lane & 15;
  const int p0 = blockIdx.x * 64;
  const int y  = blockIdx.y;
  const int b  = blockIdx.z;

  // smem: staging (2 planes x 66px x 32c = 2x4224B) / epilogue (2 x 64x72 bf16)
  __shared__ __align__(16) unsigned short smem[2 * 64 * 72];
  unsigned short* stH = smem;
  unsigned short* stL = smem + 2112;

  f32x4 acc[4];
  {
    float bv[4];
    #pragma unroll
    for (int r = 0; r < 4; ++r) {
      const int oc = wv * 16 + g * 4 + r;
      bv[r] = (EPI == 1 && oc >= 27) ? 0.f : bias[oc];
    }
    #pragma unroll
    for (int n = 0; n < 4; ++n) {
      acc[n][0] = bv[0]; acc[n][1] = bv[1]; acc[n][2] = bv[2]; acc[n][3] = bv[3];
    }
  }

  for (int ky = 0; ky < 3; ++ky) {
    const size_t rb = (((size_t)b * PR_ + (y + ky)) * PR_ + p0) * CPADI;
    for (int cc = 0; cc < NCC; ++cc) {
      __syncthreads();
      // stage 66px x 32c hi/lo, swizzled: slot s holds c-group s ^ ((px>>1)&3)
      for (int ch = tid; ch < 264; ch += NW * 64) {
        const int px = ch >> 2, s = ch & 3;
        const int cg = s ^ ((px >> 1) & 3);
        const size_t so = rb + (size_t)px * CPADI + cc * 32 + cg * 8;
        *(u32x4*)(stH + ch * 8) = *(const u32x4*)(inH + so);
        *(u32x4*)(stL + ch * 8) = *(const u32x4*)(inL + so);
      }
      __syncthreads();
      #pragma unroll
      for (int kx = 0; kx < 3; ++kx) {
        const int k = ky * 3 + kx;
        const size_t wo = ((size_t)(k * OPAD + wv * 16 + l16)) * CPADI + cc * 32 + g * 8;
        const bf16x8 aH = *(const bf16x8*)(WH + wo);
        const bf16x8 aL = *(const bf16x8*)(WL + wo);
        #pragma unroll
        for (int n = 0; n < 4; ++n) {
          const int pxt = n * 16 + l16 + kx;
          const int bo = pxt * 32 + ((g ^ ((pxt >> 1) & 3)) * 8);
          const bf16x8 bH = *(const bf16x8*)(stH + bo);
          const bf16x8 bL = *(const bf16x8*)(stL + bo);
          acc[n] = __builtin_amdgcn_mfma_f32_16x16x32_bf16(aH, bH, acc[n], 0, 0, 0);
          acc[n] = __builtin_amdgcn_mfma_f32_16x16x32_bf16(aL, bH, acc[n], 0, 0, 0);
          acc[n] = __builtin_amdgcn_mfma_f32_16x16x32_bf16(aH, bL, acc[n], 0, 0, 0);
        }
      }
    }
  }

  if (EPI == 0) {
    // lrelu -> hi/lo split -> LDS transpose -> coalesced padded-NHWC store
    __syncthreads();
    unsigned short* eH = smem;
    unsigned short* eL = smem + 64 * 72;
    #pragma unroll
    for (int n = 0; n < 4; ++n) {
      const int px = n * 16 + l16;
      #pragma unroll
      for (int r = 0; r < 4; ++r) {
        const int c = wv * 16 + g * 4 + r;
        float v = acc[n][r];
        v = (v >= 0.f) ? v : 0.1f * v;
        const unsigned short h = f2bf(v);
        eH[px * 72 + c] = h;
        eL[px * 72 + c] = f2bf(v - bf2f(h));
      }
    }
    __syncthreads();
    const int px = tid >> 2, cq = tid & 3;
    const size_t ob = (((size_t)b * PR_ + (y + 1)) * PR_ + (p0 + px + 1)) * 64 + cq * 16;
    const u32x4 h0 = *(const u32x4*)(eH + px * 72 + cq * 16);
    const u32x4 h1 = *(const u32x4*)(eH + px * 72 + cq * 16 + 8);
    const u32x4 l0 = *(const u32x4*)(eL + px * 72 + cq * 16);
    const u32x4 l1 = *(const u32x4*)(eL + px * 72 + cq * 16 + 8);
    *(u32x4*)(outH + ob)     = h0;
    *(u32x4*)(outH + ob + 8) = h1;
    *(u32x4*)(outL + ob)     = l0;
    *(u32x4*)(outL + ob + 8) = l1;
  } else {
    // conv4: offsets (10*tanh + flow_yx) / sigmoid mask -> fp32 NCHW om
    #pragma unroll
    for (int n = 0; n < 4; ++n) {
      const int px = p0 + n * 16 + l16;
      #pragma unroll
      for (int r = 0; r < 4; ++r) {
        const int oc = wv * 16 + g * 4 + r;
        if (oc >= 27) continue;
        float v = acc[n][r];
        if (oc < 18) {
          const float f = flow[(((size_t)b * 2 + ((oc & 1) ? 0 : 1)) * H_ + y) * W_ + px];
          v = 10.f * tanhf(v) + f;
        } else {
          v = 1.f / (1.f + expf(-v));
        }
        om[((size_t)(b * 27 + oc) * HW_) + (size_t)y * W_ + px] = v;
      }
    }
  }
}

// ---------------------------------------------------------------------------
// deform weight (O=64,C=64,3,3) fp32 -> W2[k][o][c] bf16
// ---------------------------------------------------------------------------
__global__ __launch_bounds__(256) void prep_w2(const float* __restrict__ w,
                                               unsigned short* __restrict__ W2)
{
  const int i = blockIdx.x * 256 + threadIdx.x;
  if (i < 64 * 64 * 9) {
    const int o = i / 576;
    const int rem = i % 576;
    const int c = rem / 9;
    const int k = rem % 9;
    W2[((size_t)k * 64 + o) * 64 + c] = f2bf(w[i]);
  }
}

// ---------------------------------------------------------------------------
// x NCHW fp32 -> NHWC bf16: xTb[b][p][c]
// ---------------------------------------------------------------------------
__global__ __launch_bounds__(256) void transpose_x(const float* __restrict__ x,
                                                   unsigned short* __restrict__ xTb)
{
  const int tid = threadIdx.x;
  const int lane = tid & 63, wv = tid >> 6;
  const int blocksPerB = HW_ / 64;
  const int b = blockIdx.x / blocksPerB;
  const int p0 = (blockIdx.x % blocksPerB) * 64;

  __shared__ float t[64][65];
  const float* xb = x + (size_t)b * C_ * HW_;
  #pragma unroll
  for (int j = 0; j < 16; ++j) {
    const int c = wv * 16 + j;
    t[c][lane] = xb[(size_t)c * HW_ + p0 + lane];
  }
  __syncthreads();
  unsigned short* xo = xTb + ((size_t)b * HW_ + p0) * 64;
  const int c4 = (tid & 15) * 4;
  const int pb = tid >> 4;
  #pragma unroll
  for (int pp = 0; pp < 4; ++pp) {
    const int p = pb + 16 * pp;
    ushort4 v = { f2bf(t[c4][p]), f2bf(t[c4+1][p]), f2bf(t[c4+2][p]), f2bf(t[c4+3][p]) };
    *(ushort4*)(xo + (size_t)p * 64 + c4) = v;
  }
}

// ---------------------------------------------------------------------------
// Deformable conv, bf16 MFMA (unchanged from round 3 — verified)
// ---------------------------------------------------------------------------
__global__ __launch_bounds__(256) void deform_k(
    const unsigned short* __restrict__ xTb, const float* __restrict__ om,
    const unsigned short* __restrict__ W2, const float* __restrict__ bias,
    float* __restrict__ out)
{
  const int tid = threadIdx.x;
  const int lane = tid & 63, wv = tid >> 6;
  const int g = lane >> 4;
  const int l16 = lane & 15;
  const int blocksPerB = HW_ / 64;
  const int b = blockIdx.x / blocksPerB;
  const int rem = blockIdx.x % blocksPerB;
  const int h = (rem * 64) / W_;
  const int w0 = (rem * 64) % W_;

  __shared__ int   ci[4][9][64];
  __shared__ float cw[4][9][64];
  __shared__ __align__(16) unsigned short valk[64 * 64];

  for (int idx = tid; idx < 9 * 64; idx += 256) {
    const int k = idx >> 6, p = idx & 63;
    const size_t base = (size_t)b * 27 * HW_ + (size_t)h * W_ + w0 + p;
    const float dy = om[base + (size_t)(2 * k) * HW_];
    const float dx = om[base + (size_t)(2 * k + 1) * HW_];
    const float m  = om[base + (size_t)(18 + k) * HW_];
    const int ky = k / 3, kx = k - ky * 3;
    const float py = dy + (float)(h - 1 + ky);
    const float px = dx + (float)(w0 + p - 1 + kx);
    const float y0f = floorf(py), x0f = floorf(px);
    const float ly = py - y0f, lx = px - x0f;
    const int y0 = (int)y0f, x0 = (int)x0f;
    const int y1 = y0 + 1, x1 = x0 + 1;
    float w00 = (1.f - ly) * (1.f - lx), w01 = (1.f - ly) * lx;
    float w10 = ly * (1.f - lx),        w11 = ly * lx;
    if (!(y0 >= 0 && y0 < H_)) { w00 = 0.f; w01 = 0.f; }
    if (!(y1 >= 0 && y1 < H_)) { w10 = 0.f; w11 = 0.f; }
    if (!(x0 >= 0 && x0 < W_)) { w00 = 0.f; w10 = 0.f; }
    if (!(x1 >= 0 && x1 < W_)) { w01 = 0.f; w11 = 0.f; }
    const int yc0 = min(max(y0, 0), H_ - 1), yc1 = min(max(y1, 0), H_ - 1);
    const int xc0 = min(max(x0, 0), W_ - 1), xc1 = min(max(x1, 0), W_ - 1);
    ci[0][k][p] = yc0 * W_ + xc0;  cw[0][k][p] = m * w00;
    ci[1][k][p] = yc0 * W_ + xc1;  cw[1][k][p] = m * w01;
    ci[2][k][p] = yc1 * W_ + xc0;  cw[2][k][p] = m * w10;
    ci[3][k][p] = yc1 * W_ + xc1;  cw[3][k][p] = m * w11;
  }

  f32x4 acc[4];
  {
    float br[4];
    #pragma unroll
    for (int r = 0; r < 4; ++r) br[r] = bias[wv * 16 + g * 4 + r];
    #pragma unroll
    for (int n = 0; n < 4; ++n) { acc[n][0]=br[0]; acc[n][1]=br[1]; acc[n][2]=br[2]; acc[n][3]=br[3]; }
  }

  const unsigned short* xb = xTb + (size_t)b * HW_ * 64;
  __syncthreads();

  for (int k = 0; k < 9; ++k) {
    #pragma unroll
    for (int i = 0; i < 2; ++i) {
      const int it = tid + (i << 8);
      const int cg = it & 7, p = it >> 3;
      const int i00 = ci[0][k][p], i01 = ci[1][k][p];
      const int i10 = ci[2][k][p], i11 = ci[3][k][p];
      const float q00 = cw[0][k][p], q01 = cw[1][k][p];
      const float q10 = cw[2][k][p], q11 = cw[3][k][p];
      const u32x4 va = *(const u32x4*)(xb + ((size_t)i00 * 64 + cg * 8));
      const u32x4 vb = *(const u32x4*)(xb + ((size_t)i01 * 64 + cg * 8));
      const u32x4 vc = *(const u32x4*)(xb + ((size_t)i10 * 64 + cg * 8));
      const u32x4 vd = *(const u32x4*)(xb + ((size_t)i11 * 64 + cg * 8));
      u32x4 res;
      #pragma unroll
      for (int j = 0; j < 4; ++j) {
        const float lo = q00*bflo(va[j]) + q01*bflo(vb[j]) + q10*bflo(vc[j]) + q11*bflo(vd[j]);
        const float hi = q00*bfhi(va[j]) + q01*bfhi(vb[j]) + q10*bfhi(vc[j]) + q11*bfhi(vd[j]);
        res[j] = pkbf(lo, hi);
      }
      *(u32x4*)&valk[(p << 6) + ((cg ^ (p & 7)) << 3)] = res;
    }

    const unsigned short* w2t = W2 + ((size_t)k * 64 + wv * 16 + l16) * 64 + g * 8;
    const bf16x8 a0 = *(const bf16x8*)(w2t);
    const bf16x8 a1 = *(const bf16x8*)(w2t + 32);

    __syncthreads();

    #pragma unroll
    for (int n = 0; n < 4; ++n) {
      const int p = n * 16 + l16;
      const bf16x8 b0 = *(const bf16x8*)&valk[(p << 6) + (((g    ) ^ (p & 7)) << 3)];
      const bf16x8 b1 = *(const bf16x8*)&valk[(p << 6) + (((g + 4) ^ (p & 7)) << 3)];
      acc[n] = __builtin_amdgcn_mfma_f32_16x16x32_bf16(a0, b0, acc[n], 0, 0, 0);
      acc[n] = __builtin_amdgcn_mfma_f32_16x16x32_bf16(a1, b1, acc[n], 0, 0, 0);
    }
    __syncthreads();
  }

  #pragma unroll
  for (int n = 0; n < 4; ++n) {
    #pragma unroll
    for (int r = 0; r < 4; ++r) {
      const int oc = wv * 16 + g * 4 + r;
      out[((size_t)(b * C_ + oc) * HW_) + (size_t)h * W_ + w0 + n * 16 + l16] = acc[n][r];
    }
  }
}

// ---------------------------------------------------------------------------
extern "C" void kernel_launch(void* const* d_in, const int* in_sizes, int n_in,
                              void* d_out, int out_size, void* d_ws, size_t ws_size,
                              hipStream_t stream) {
  const float* x         = (const float*)d_in[0];
  const float* cond_feat = (const float*)d_in[1];
  const float* flow      = (const float*)d_in[2];
  const float* w1 = (const float*)d_in[3];  const float* b1 = (const float*)d_in[4];
  const float* w2 = (const float*)d_in[5];  const float* b2 = (const float*)d_in[6];
  const float* w3 = (const float*)d_in[7];  const float* b3 = (const float*)d_in[8];
  const float* w4 = (const float*)d_in[9];  const float* b4 = (const float*)d_in[10];
  const float* wgt = (const float*)d_in[11]; const float* bias = (const float*)d_in[12];

  float* outp = (float*)d_out;

  // workspace layout (256B-aligned chunks)
  char* wsp = (char*)d_ws;
  size_t off = 0;
  auto alloc = [&](size_t bytes) { char* p = wsp + off; off += (bytes + 255) & ~(size_t)255; return p; };
  const size_t padHW = (size_t)PR_ * PR_;                       // 37636
  unsigned short* condH = (unsigned short*)alloc(B_ * padHW * 160 * 2);
  unsigned short* condL = (unsigned short*)alloc(B_ * padHW * 160 * 2);
  unsigned short* hA_H  = (unsigned short*)alloc(B_ * padHW * 64 * 2);
  unsigned short* hA_L  = (unsigned short*)alloc(B_ * padHW * 64 * 2);
  unsigned short* hB_H  = (unsigned short*)alloc(B_ * padHW * 64 * 2);
  unsigned short* hB_L  = (unsigned short*)alloc(B_ * padHW * 64 * 2);
  float*          om    = (float*)alloc((size_t)B_ * 27 * HW_ * 4);
  unsigned short* xTb   = (unsigned short*)alloc((size_t)B_ * HW_ * 64 * 2);
  unsigned short* W2d   = (unsigned short*)alloc(9 * 64 * 64 * 2);
  unsigned short* W1H   = (unsigned short*)alloc(9 * 64 * 160 * 2);
  unsigned short* W1L   = (unsigned short*)alloc(9 * 64 * 160 * 2);
  unsigned short* W2H   = (unsigned short*)alloc(9 * 64 * 64 * 2);
  unsigned short* W2L   = (unsigned short*)alloc(9 * 64 * 64 * 2);
  unsigned short* W3H   = (unsigned short*)alloc(9 * 64 * 64 * 2);
  unsigned short* W3L   = (unsigned short*)alloc(9 * 64 * 64 * 2);
  unsigned short* W4H   = (unsigned short*)alloc(9 * 32 * 64 * 2);
  unsigned short* W4L   = (unsigned short*)alloc(9 * 32 * 64 * 2);

  // weight prep
  prep_cw<64, 131, 64, 160><<<(9*64*160 + 255)/256, 256, 0, stream>>>(w1, W1H, W1L);
  prep_cw<64, 64, 64, 64><<<(9*64*64 + 255)/256, 256, 0, stream>>>(w2, W2H, W2L);
  prep_cw<64, 64, 64, 64><<<(9*64*64 + 255)/256, 256, 0, stream>>>(w3, W3H, W3L);
  prep_cw<27, 64, 32, 64><<<(9*32*64 + 255)/256, 256, 0, stream>>>(w4, W4H, W4L);
  prep_w2<<<144, 256, 0, stream>>>(wgt, W2d);

  // input prep
  transpose_cond<<<B_ * PR_, 256, 0, stream>>>(cond_feat, condH, condL);
  halo_zero<<<(B_ * PR_ * PR_ + 255)/256, 256, 0, stream>>>(hA_H, hA_L);
  halo_zero<<<(B_ * PR_ * PR_ + 255)/256, 256, 0, stream>>>(hB_H, hB_L);
  transpose_x<<<(B_ * HW_)/64, 256, 0, stream>>>(x, xTb);

  // conv chain (MFMA)
  dim3 cg(3, 192, 2);
  conv_mfma<5, 4, 0, 160><<<cg, 256, 0, stream>>>(condH, condL, W1H, W1L, b1, nullptr, hA_H, hA_L, nullptr);
  conv_mfma<2, 4, 0, 64><<<cg, 256, 0, stream>>>(hA_H, hA_L, W2H, W2L, b2, nullptr, hB_H, hB_L, nullptr);
  conv_mfma<2, 4, 0, 64><<<cg, 256, 0, stream>>>(hB_H, hB_L, W3H, W3L, b3, nullptr, hA_H, hA_L, nullptr);
  conv_mfma<2, 2, 1, 64><<<cg, 128, 0, stream>>>(hA_H, hA_L, W4H, W4L, b4, flow, nullptr, nullptr, om);

  // deformable conv
  deform_k<<<(B_ * HW_)/64, 256, 0, stream>>>(xTb, om, W2d, bias, outp);
}

// Round 5
// 240.832 us; speedup vs baseline: 4.7403x; 1.0697x over previous
//
#include <hip/hip_runtime.h>
#include <math.h>

#define B_ 2
#define C_ 64
#define H_ 192
#define W_ 192
#define HW_ (H_*W_)
#define PR_ 194      // padded row length (W+2)

typedef __attribute__((ext_vector_type(8))) short    bf16x8;
typedef __attribute__((ext_vector_type(4))) float    f32x4;
typedef __attribute__((ext_vector_type(4))) unsigned u32x4;

__device__ inline unsigned short f2bf(float f) {           // RNE fp32->bf16
  unsigned u = __float_as_uint(f);
  return (unsigned short)((u + 0x7fffu + ((u >> 16) & 1u)) >> 16);
}
__device__ inline float bf2f(unsigned short h) { return __uint_as_float((unsigned)h << 16); }
__device__ inline float bflo(unsigned u) { return __uint_as_float(u << 16); }
__device__ inline float bfhi(unsigned u) { return __uint_as_float(u & 0xffff0000u); }
__device__ inline unsigned pkbf(float a, float b) {
  unsigned ua = __float_as_uint(a), ub = __float_as_uint(b);
  ua = (ua + 0x7fffu + ((ua >> 16) & 1u)) >> 16;
  ub = (ub + 0x7fffu + ((ub >> 16) & 1u)) >> 16;
  return ua | (ub << 16);
}

// ---------------------------------------------------------------------------
// conv weight OIHW fp32 -> [k][o][c] hi/lo bf16 planes (zero-padded o,c)
// ---------------------------------------------------------------------------
template<int O, int CIN, int OPAD, int CPAD>
__global__ __launch_bounds__(256) void prep_cw(const float* __restrict__ w,
                                               unsigned short* __restrict__ WH,
                                               unsigned short* __restrict__ WL)
{
  const int i = blockIdx.x * 256 + threadIdx.x;
  if (i >= 9 * OPAD * CPAD) return;
  const int k = i / (OPAD * CPAD);
  const int r = i % (OPAD * CPAD);
  const int o = r / CPAD;
  const int c = r % CPAD;
  float v = (o < O && c < CIN) ? w[((size_t)o * CIN + c) * 9 + k] : 0.f;
  const unsigned short h = f2bf(v);
  WH[i] = h;
  WL[i] = f2bf(v - bf2f(h));
}

// ---------------------------------------------------------------------------
// cond_feat fp32 NCHW (131ch) -> chunked padded NHWC-32 hi/lo bf16:
// layout [b][cc(5)][194][194][32]. One block per (b, padded row).
// All global writes are contiguous 16B segments across consecutive threads.
// ---------------------------------------------------------------------------
__global__ __launch_bounds__(256) void transpose_cond(const float* __restrict__ cond,
                                                      unsigned short* __restrict__ cH,
                                                      unsigned short* __restrict__ cL)
{
  const int tid = threadIdx.x;
  const int b  = blockIdx.x / PR_;
  const int yp = blockIdx.x % PR_;

  if (yp == 0 || yp == PR_ - 1) {                 // halo row: all zeros
    u32x4 z = {0, 0, 0, 0};
    for (int cc = 0; cc < 5; ++cc) {
      const size_t ob = (((size_t)(b * 5 + cc) * PR_ + yp) * PR_) * 32;
      for (int idx = tid; idx < PR_ * 4; idx += 256) {
        *(u32x4*)(cH + ob + (size_t)idx * 8) = z;
        *(u32x4*)(cL + ob + (size_t)idx * 8) = z;
      }
    }
    return;
  }
  const int y = yp - 1;
  __shared__ float t[32][PR_];

  for (int cc = 0; cc < 5; ++cc) {
    __syncthreads();
    for (int idx = tid; idx < 32 * 192; idx += 256) {
      const int ci = idx / 192, px = idx % 192;
      const int c = cc * 32 + ci;
      t[ci][px + 1] = (c < 131) ? cond[(((size_t)b * 131 + c) * H_ + y) * W_ + px] : 0.f;
    }
    if (tid < 32) { t[tid][0] = 0.f; t[tid][PR_ - 1] = 0.f; }
    __syncthreads();
    const size_t ob = (((size_t)(b * 5 + cc) * PR_ + yp) * PR_) * 32;
    for (int idx = tid; idx < PR_ * 4; idx += 256) {   // (px, 8ch-seg)
      const int px = idx >> 2, sg = idx & 3;
      u32x4 vh, vl;
      #pragma unroll
      for (int q = 0; q < 4; ++q) {
        const int c0 = sg * 8 + q * 2;
        const float va = t[c0][px], vb = t[c0 + 1][px];
        const unsigned short ha = f2bf(va), hb = f2bf(vb);
        vh[q] = (unsigned)ha | ((unsigned)hb << 16);
        const unsigned short la = f2bf(va - bf2f(ha)), lb = f2bf(vb - bf2f(hb));
        vl[q] = (unsigned)la | ((unsigned)lb << 16);
      }
      *(u32x4*)(cH + ob + (size_t)idx * 8) = vh;
      *(u32x4*)(cL + ob + (size_t)idx * 8) = vl;
    }
  }
}

// ---------------------------------------------------------------------------
// zero halo of chunked padded NHWC-32 hi/lo pair ([b][2][194][194][32])
// ---------------------------------------------------------------------------
__global__ __launch_bounds__(256) void halo_zero(unsigned short* __restrict__ H,
                                                 unsigned short* __restrict__ L)
{
  const int idx = blockIdx.x * 256 + threadIdx.x;
  if (idx >= B_ * 2 * PR_ * PR_) return;
  const int r  = idx % (PR_ * PR_);
  const int yp = r / PR_, xp = r % PR_;
  if (yp == 0 || yp == PR_ - 1 || xp == 0 || xp == PR_ - 1) {
    u32x4 z = {0, 0, 0, 0};
    const size_t base = (size_t)idx * 32;
    #pragma unroll
    for (int j = 0; j < 4; ++j) {
      *(u32x4*)(H + base + j * 8) = z;
      *(u32x4*)(L + base + j * 8) = z;
    }
  }
}

// ---------------------------------------------------------------------------
// MFMA 3x3 conv on chunked padded NHWC-32 hi/lo bf16. Tile 64px x (NW*16) oc.
// 3-term hi/lo MFMA: W_h*x_h + W_l*x_h + W_h*x_l (fp32 acc).
// EPI 0: lrelu -> hi/lo split -> chunked padded store (via LDS transpose).
// EPI 1: conv4 offsets/mask epilogue -> fp32 NCHW om (27 ch).
// CW = weight c-stride (160 for conv1, 64 otherwise).
// ---------------------------------------------------------------------------
template<int NCC, int NW, int EPI, int CW>
__global__ __launch_bounds__(NW * 64) void conv_mfma(
    const unsigned short* __restrict__ inH, const unsigned short* __restrict__ inL,
    const unsigned short* __restrict__ WH, const unsigned short* __restrict__ WL,
    const float* __restrict__ bias, const float* __restrict__ flow,
    unsigned short* __restrict__ outH, unsigned short* __restrict__ outL,
    float* __restrict__ om)
{
  constexpr int OPAD = NW * 16;
  const int tid = threadIdx.x;
  const int lane = tid & 63, wv = tid >> 6;
  const int g = lane >> 4, l16 = lane & 15;
  const int p0 = blockIdx.x * 64;
  const int y  = blockIdx.y;
  const int b  = blockIdx.z;

  // smem: staging (2 planes x 66px x 32c) / epilogue (2 x 64x72 bf16)
  __shared__ __align__(16) unsigned short smem[2 * 64 * 72];
  unsigned short* stH = smem;
  unsigned short* stL = smem + 2112;

  f32x4 acc[4];
  {
    float bv[4];
    #pragma unroll
    for (int r = 0; r < 4; ++r) {
      const int oc = wv * 16 + g * 4 + r;
      bv[r] = (EPI == 1 && oc >= 27) ? 0.f : bias[oc];
    }
    #pragma unroll
    for (int n = 0; n < 4; ++n) {
      acc[n][0] = bv[0]; acc[n][1] = bv[1]; acc[n][2] = bv[2]; acc[n][3] = bv[3];
    }
  }

  for (int ky = 0; ky < 3; ++ky) {
    for (int cc = 0; cc < NCC; ++cc) {
      const size_t rb = ((((size_t)b * NCC + cc) * PR_ + (y + ky)) * PR_ + p0) * 32;
      __syncthreads();
      // stage 66px x 32c hi/lo, swizzled: slot s holds c-group s ^ ((px>>1)&3)
      for (int ch = tid; ch < 264; ch += NW * 64) {
        const int px = ch >> 2, s = ch & 3;
        const int cg = s ^ ((px >> 1) & 3);
        const size_t so = rb + (size_t)px * 32 + cg * 8;
        *(u32x4*)(stH + ch * 8) = *(const u32x4*)(inH + so);
        *(u32x4*)(stL + ch * 8) = *(const u32x4*)(inL + so);
      }
      __syncthreads();
      #pragma unroll
      for (int kx = 0; kx < 3; ++kx) {
        const int k = ky * 3 + kx;
        const size_t wo = ((size_t)(k * OPAD + wv * 16 + l16)) * CW + cc * 32 + g * 8;
        const bf16x8 aH = *(const bf16x8*)(WH + wo);
        const bf16x8 aL = *(const bf16x8*)(WL + wo);
        #pragma unroll
        for (int n = 0; n < 4; ++n) {
          const int pxt = n * 16 + l16 + kx;
          const int bo = pxt * 32 + ((g ^ ((pxt >> 1) & 3)) * 8);
          const bf16x8 bH = *(const bf16x8*)(stH + bo);
          const bf16x8 bL = *(const bf16x8*)(stL + bo);
          acc[n] = __builtin_amdgcn_mfma_f32_16x16x32_bf16(aH, bH, acc[n], 0, 0, 0);
          acc[n] = __builtin_amdgcn_mfma_f32_16x16x32_bf16(aL, bH, acc[n], 0, 0, 0);
          acc[n] = __builtin_amdgcn_mfma_f32_16x16x32_bf16(aH, bL, acc[n], 0, 0, 0);
        }
      }
    }
  }

  if (EPI == 0) {
    // lrelu -> hi/lo split -> LDS transpose -> coalesced chunked store
    __syncthreads();
    unsigned short* eH = smem;
    unsigned short* eL = smem + 64 * 72;
    #pragma unroll
    for (int n = 0; n < 4; ++n) {
      const int px = n * 16 + l16;
      #pragma unroll
      for (int r = 0; r < 4; ++r) {
        const int c = wv * 16 + g * 4 + r;
        float v = acc[n][r];
        v = (v >= 0.f) ? v : 0.1f * v;
        const unsigned short h = f2bf(v);
        eH[px * 72 + c] = h;
        eL[px * 72 + c] = f2bf(v - bf2f(h));
      }
    }
    __syncthreads();
    const int px = tid >> 2, cq = tid & 3;
    const int cc = cq >> 1;
    const size_t ob = ((((size_t)b * 2 + cc) * PR_ + (y + 1)) * PR_ + (p0 + px + 1)) * 32
                    + (cq & 1) * 16;
    const u32x4 h0 = *(const u32x4*)(eH + px * 72 + cq * 16);
    const u32x4 h1 = *(const u32x4*)(eH + px * 72 + cq * 16 + 8);
    const u32x4 l0 = *(const u32x4*)(eL + px * 72 + cq * 16);
    const u32x4 l1 = *(const u32x4*)(eL + px * 72 + cq * 16 + 8);
    *(u32x4*)(outH + ob)     = h0;
    *(u32x4*)(outH + ob + 8) = h1;
    *(u32x4*)(outL + ob)     = l0;
    *(u32x4*)(outL + ob + 8) = l1;
  } else {
    // conv4: offsets (10*tanh + flow_yx) / sigmoid mask -> fp32 NCHW om
    #pragma unroll
    for (int n = 0; n < 4; ++n) {
      const int px = p0 + n * 16 + l16;
      #pragma unroll
      for (int r = 0; r < 4; ++r) {
        const int oc = wv * 16 + g * 4 + r;
        if (oc >= 27) continue;
        float v = acc[n][r];
        if (oc < 18) {
          const float f = flow[(((size_t)b * 2 + ((oc & 1) ? 0 : 1)) * H_ + y) * W_ + px];
          v = 10.f * tanhf(v) + f;
        } else {
          v = 1.f / (1.f + expf(-v));
        }
        om[((size_t)(b * 27 + oc) * HW_) + (size_t)y * W_ + px] = v;
      }
    }
  }
}

// ---------------------------------------------------------------------------
// deform weight (O=64,C=64,3,3) fp32 -> W2[k][o][c] bf16
// ---------------------------------------------------------------------------
__global__ __launch_bounds__(256) void prep_w2(const float* __restrict__ w,
                                               unsigned short* __restrict__ W2)
{
  const int i = blockIdx.x * 256 + threadIdx.x;
  if (i < 64 * 64 * 9) {
    const int o = i / 576;
    const int rem = i % 576;
    const int c = rem / 9;
    const int k = rem % 9;
    W2[((size_t)k * 64 + o) * 64 + c] = f2bf(w[i]);
  }
}

// ---------------------------------------------------------------------------
// x NCHW fp32 -> NHWC bf16: xTb[b][p][c]
// ---------------------------------------------------------------------------
__global__ __launch_bounds__(256) void transpose_x(const float* __restrict__ x,
                                                   unsigned short* __restrict__ xTb)
{
  const int tid = threadIdx.x;
  const int lane = tid & 63, wv = tid >> 6;
  const int blocksPerB = HW_ / 64;
  const int b = blockIdx.x / blocksPerB;
  const int p0 = (blockIdx.x % blocksPerB) * 64;

  __shared__ float t[64][65];
  const float* xb = x + (size_t)b * C_ * HW_;
  #pragma unroll
  for (int j = 0; j < 16; ++j) {
    const int c = wv * 16 + j;
    t[c][lane] = xb[(size_t)c * HW_ + p0 + lane];
  }
  __syncthreads();
  unsigned short* xo = xTb + ((size_t)b * HW_ + p0) * 64;
  const int c4 = (tid & 15) * 4;
  const int pb = tid >> 4;
  #pragma unroll
  for (int pp = 0; pp < 4; ++pp) {
    const int p = pb + 16 * pp;
    ushort4 v = { f2bf(t[c4][p]), f2bf(t[c4+1][p]), f2bf(t[c4+2][p]), f2bf(t[c4+3][p]) };
    *(ushort4*)(xo + (size_t)p * 64 + c4) = v;
  }
}

// ---------------------------------------------------------------------------
// Deformable conv, bf16 MFMA (unchanged — verified)
// ---------------------------------------------------------------------------
__global__ __launch_bounds__(256) void deform_k(
    const unsigned short* __restrict__ xTb, const float* __restrict__ om,
    const unsigned short* __restrict__ W2, const float* __restrict__ bias,
    float* __restrict__ out)
{
  const int tid = threadIdx.x;
  const int lane = tid & 63, wv = tid >> 6;
  const int g = lane >> 4;
  const int l16 = lane & 15;
  const int blocksPerB = HW_ / 64;
  const int b = blockIdx.x / blocksPerB;
  const int rem = blockIdx.x % blocksPerB;
  const int h = (rem * 64) / W_;
  const int w0 = (rem * 64) % W_;

  __shared__ int   ci[4][9][64];
  __shared__ float cw[4][9][64];
  __shared__ __align__(16) unsigned short valk[64 * 64];

  for (int idx = tid; idx < 9 * 64; idx += 256) {
    const int k = idx >> 6, p = idx & 63;
    const size_t base = (size_t)b * 27 * HW_ + (size_t)h * W_ + w0 + p;
    const float dy = om[base + (size_t)(2 * k) * HW_];
    const float dx = om[base + (size_t)(2 * k + 1) * HW_];
    const float m  = om[base + (size_t)(18 + k) * HW_];
    const int ky = k / 3, kx = k - ky * 3;
    const float py = dy + (float)(h - 1 + ky);
    const float px = dx + (float)(w0 + p - 1 + kx);
    const float y0f = floorf(py), x0f = floorf(px);
    const float ly = py - y0f, lx = px - x0f;
    const int y0 = (int)y0f, x0 = (int)x0f;
    const int y1 = y0 + 1, x1 = x0 + 1;
    float w00 = (1.f - ly) * (1.f - lx), w01 = (1.f - ly) * lx;
    float w10 = ly * (1.f - lx),        w11 = ly * lx;
    if (!(y0 >= 0 && y0 < H_)) { w00 = 0.f; w01 = 0.f; }
    if (!(y1 >= 0 && y1 < H_)) { w10 = 0.f; w11 = 0.f; }
    if (!(x0 >= 0 && x0 < W_)) { w00 = 0.f; w10 = 0.f; }
    if (!(x1 >= 0 && x1 < W_)) { w01 = 0.f; w11 = 0.f; }
    const int yc0 = min(max(y0, 0), H_ - 1), yc1 = min(max(y1, 0), H_ - 1);
    const int xc0 = min(max(x0, 0), W_ - 1), xc1 = min(max(x1, 0), W_ - 1);
    ci[0][k][p] = yc0 * W_ + xc0;  cw[0][k][p] = m * w00;
    ci[1][k][p] = yc0 * W_ + xc1;  cw[1][k][p] = m * w01;
    ci[2][k][p] = yc1 * W_ + xc0;  cw[2][k][p] = m * w10;
    ci[3][k][p] = yc1 * W_ + xc1;  cw[3][k][p] = m * w11;
  }

  f32x4 acc[4];
  {
    float br[4];
    #pragma unroll
    for (int r = 0; r < 4; ++r) br[r] = bias[wv * 16 + g * 4 + r];
    #pragma unroll
    for (int n = 0; n < 4; ++n) { acc[n][0]=br[0]; acc[n][1]=br[1]; acc[n][2]=br[2]; acc[n][3]=br[3]; }
  }

  const unsigned short* xb = xTb + (size_t)b * HW_ * 64;
  __syncthreads();

  for (int k = 0; k < 9; ++k) {
    #pragma unroll
    for (int i = 0; i < 2; ++i) {
      const int it = tid + (i << 8);
      const int cg = it & 7, p = it >> 3;
      const int i00 = ci[0][k][p], i01 = ci[1][k][p];
      const int i10 = ci[2][k][p], i11 = ci[3][k][p];
      const float q00 = cw[0][k][p], q01 = cw[1][k][p];
      const float q10 = cw[2][k][p], q11 = cw[3][k][p];
      const u32x4 va = *(const u32x4*)(xb + ((size_t)i00 * 64 + cg * 8));
      const u32x4 vb = *(const u32x4*)(xb + ((size_t)i01 * 64 + cg * 8));
      const u32x4 vc = *(const u32x4*)(xb + ((size_t)i10 * 64 + cg * 8));
      const u32x4 vd = *(const u32x4*)(xb + ((size_t)i11 * 64 + cg * 8));
      u32x4 res;
      #pragma unroll
      for (int j = 0; j < 4; ++j) {
        const float lo = q00*bflo(va[j]) + q01*bflo(vb[j]) + q10*bflo(vc[j]) + q11*bflo(vd[j]);
        const float hi = q00*bfhi(va[j]) + q01*bfhi(vb[j]) + q10*bfhi(vc[j]) + q11*bfhi(vd[j]);
        res[j] = pkbf(lo, hi);
      }
      *(u32x4*)&valk[(p << 6) + ((cg ^ (p & 7)) << 3)] = res;
    }

    const unsigned short* w2t = W2 + ((size_t)k * 64 + wv * 16 + l16) * 64 + g * 8;
    const bf16x8 a0 = *(const bf16x8*)(w2t);
    const bf16x8 a1 = *(const bf16x8*)(w2t + 32);

    __syncthreads();

    #pragma unroll
    for (int n = 0; n < 4; ++n) {
      const int p = n * 16 + l16;
      const bf16x8 b0 = *(const bf16x8*)&valk[(p << 6) + (((g    ) ^ (p & 7)) << 3)];
      const bf16x8 b1 = *(const bf16x8*)&valk[(p << 6) + (((g + 4) ^ (p & 7)) << 3)];
      acc[n] = __builtin_amdgcn_mfma_f32_16x16x32_bf16(a0, b0, acc[n], 0, 0, 0);
      acc[n] = __builtin_amdgcn_mfma_f32_16x16x32_bf16(a1, b1, acc[n], 0, 0, 0);
    }
    __syncthreads();
  }

  #pragma unroll
  for (int n = 0; n < 4; ++n) {
    #pragma unroll
    for (int r = 0; r < 4; ++r) {
      const int oc = wv * 16 + g * 4 + r;
      out[((size_t)(b * C_ + oc) * HW_) + (size_t)h * W_ + w0 + n * 16 + l16] = acc[n][r];
    }
  }
}

// ---------------------------------------------------------------------------
extern "C" void kernel_launch(void* const* d_in, const int* in_sizes, int n_in,
                              void* d_out, int out_size, void* d_ws, size_t ws_size,
                              hipStream_t stream) {
  const float* x         = (const float*)d_in[0];
  const float* cond_feat = (const float*)d_in[1];
  const float* flow      = (const float*)d_in[2];
  const float* w1 = (const float*)d_in[3];  const float* b1 = (const float*)d_in[4];
  const float* w2 = (const float*)d_in[5];  const float* b2 = (const float*)d_in[6];
  const float* w3 = (const float*)d_in[7];  const float* b3 = (const float*)d_in[8];
  const float* w4 = (const float*)d_in[9];  const float* b4 = (const float*)d_in[10];
  const float* wgt = (const float*)d_in[11]; const float* bias = (const float*)d_in[12];

  float* outp = (float*)d_out;

  // workspace layout (256B-aligned chunks)
  char* wsp = (char*)d_ws;
  size_t off = 0;
  auto alloc = [&](size_t bytes) { char* p = wsp + off; off += (bytes + 255) & ~(size_t)255; return p; };
  const size_t padHW = (size_t)PR_ * PR_;                       // 37636
  unsigned short* condH = (unsigned short*)alloc(B_ * 5 * padHW * 32 * 2);
  unsigned short* condL = (unsigned short*)alloc(B_ * 5 * padHW * 32 * 2);
  unsigned short* hA_H  = (unsigned short*)alloc(B_ * 2 * padHW * 32 * 2);
  unsigned short* hA_L  = (unsigned short*)alloc(B_ * 2 * padHW * 32 * 2);
  unsigned short* hB_H  = (unsigned short*)alloc(B_ * 2 * padHW * 32 * 2);
  unsigned short* hB_L  = (unsigned short*)alloc(B_ * 2 * padHW * 32 * 2);
  float*          om    = (float*)alloc((size_t)B_ * 27 * HW_ * 4);
  unsigned short* xTb   = (unsigned short*)alloc((size_t)B_ * HW_ * 64 * 2);
  unsigned short* W2d   = (unsigned short*)alloc(9 * 64 * 64 * 2);
  unsigned short* W1H   = (unsigned short*)alloc(9 * 64 * 160 * 2);
  unsigned short* W1L   = (unsigned short*)alloc(9 * 64 * 160 * 2);
  unsigned short* W2H   = (unsigned short*)alloc(9 * 64 * 64 * 2);
  unsigned short* W2L   = (unsigned short*)alloc(9 * 64 * 64 * 2);
  unsigned short* W3H   = (unsigned short*)alloc(9 * 64 * 64 * 2);
  unsigned short* W3L   = (unsigned short*)alloc(9 * 64 * 64 * 2);
  unsigned short* W4H   = (unsigned short*)alloc(9 * 32 * 64 * 2);
  unsigned short* W4L   = (unsigned short*)alloc(9 * 32 * 64 * 2);

  // weight prep
  prep_cw<64, 131, 64, 160><<<(9*64*160 + 255)/256, 256, 0, stream>>>(w1, W1H, W1L);
  prep_cw<64, 64, 64, 64><<<(9*64*64 + 255)/256, 256, 0, stream>>>(w2, W2H, W2L);
  prep_cw<64, 64, 64, 64><<<(9*64*64 + 255)/256, 256, 0, stream>>>(w3, W3H, W3L);
  prep_cw<27, 64, 32, 64><<<(9*32*64 + 255)/256, 256, 0, stream>>>(w4, W4H, W4L);
  prep_w2<<<144, 256, 0, stream>>>(wgt, W2d);

  // input prep
  transpose_cond<<<B_ * PR_, 256, 0, stream>>>(cond_feat, condH, condL);
  halo_zero<<<(B_ * 2 * PR_ * PR_ + 255)/256, 256, 0, stream>>>(hA_H, hA_L);
  halo_zero<<<(B_ * 2 * PR_ * PR_ + 255)/256, 256, 0, stream>>>(hB_H, hB_L);
  transpose_x<<<(B_ * HW_)/64, 256, 0, stream>>>(x, xTb);

  // conv chain (MFMA)
  dim3 cg(3, 192, 2);
  conv_mfma<5, 4, 0, 160><<<cg, 256, 0, stream>>>(condH, condL, W1H, W1L, b1, nullptr, hA_H, hA_L, nullptr);
  conv_mfma<2, 4, 0, 64><<<cg, 256, 0, stream>>>(hA_H, hA_L, W2H, W2L, b2, nullptr, hB_H, hB_L, nullptr);
  conv_mfma<2, 4, 0, 64><<<cg, 256, 0, stream>>>(hB_H, hB_L, W3H, W3L, b3, nullptr, hA_H, hA_L, nullptr);
  conv_mfma<2, 2, 1, 64><<<cg, 128, 0, stream>>>(hA_H, hA_L, W4H, W4L, b4, flow, nullptr, nullptr, om);

  // deformable conv
  deform_k<<<(B_ * HW_)/64, 256, 0, stream>>>(xTb, om, W2d, bias, outp);
}

// Round 6
// 206.886 us; speedup vs baseline: 5.5182x; 1.1641x over previous
//
#include <hip/hip_runtime.h>
#include <math.h>

#define B_ 2
#define C_ 64
#define H_ 192
#define W_ 192
#define HW_ (H_*W_)
#define PR_ 194      // padded row length (W+2)

typedef __attribute__((ext_vector_type(8))) short    bf16x8;
typedef __attribute__((ext_vector_type(4))) float    f32x4;
typedef __attribute__((ext_vector_type(4))) unsigned u32x4;

__device__ inline unsigned short f2bf(float f) {           // RNE fp32->bf16
  unsigned u = __float_as_uint(f);
  return (unsigned short)((u + 0x7fffu + ((u >> 16) & 1u)) >> 16);
}
__device__ inline float bf2f(unsigned short h) { return __uint_as_float((unsigned)h << 16); }
__device__ inline float bflo(unsigned u) { return __uint_as_float(u << 16); }
__device__ inline float bfhi(unsigned u) { return __uint_as_float(u & 0xffff0000u); }
__device__ inline unsigned pkbf(float a, float b) {
  unsigned ua = __float_as_uint(a), ub = __float_as_uint(b);
  ua = (ua + 0x7fffu + ((ua >> 16) & 1u)) >> 16;
  ub = (ub + 0x7fffu + ((ub >> 16) & 1u)) >> 16;
  return ua | (ub << 16);
}

// ---------------------------------------------------------------------------
// conv weight OIHW fp32 -> [k][o][c] hi/lo bf16 planes (zero-padded o,c)
// ---------------------------------------------------------------------------
template<int O, int CIN, int OPAD, int CPAD>
__global__ __launch_bounds__(256) void prep_cw(const float* __restrict__ w,
                                               unsigned short* __restrict__ WH,
                                               unsigned short* __restrict__ WL)
{
  const int i = blockIdx.x * 256 + threadIdx.x;
  if (i >= 9 * OPAD * CPAD) return;
  const int k = i / (OPAD * CPAD);
  const int r = i % (OPAD * CPAD);
  const int o = r / CPAD;
  const int c = r % CPAD;
  float v = (o < O && c < CIN) ? w[((size_t)o * CIN + c) * 9 + k] : 0.f;
  const unsigned short h = f2bf(v);
  WH[i] = h;
  WL[i] = f2bf(v - bf2f(h));
}

// ---------------------------------------------------------------------------
// cond_feat fp32 NCHW (131ch) -> chunked padded NHWC-32 hi/lo bf16:
// layout [b][cc(5)][194][194][32]. One block per (b, padded row, cc-chunk):
// grid (B_*PR_, 5) — 1940 blocks for parallelism (round-5 was 388, 13% occ).
// ---------------------------------------------------------------------------
__global__ __launch_bounds__(256) void transpose_cond(const float* __restrict__ cond,
                                                      unsigned short* __restrict__ cH,
                                                      unsigned short* __restrict__ cL)
{
  const int tid = threadIdx.x;
  const int b  = blockIdx.x / PR_;
  const int yp = blockIdx.x % PR_;
  const int cc = blockIdx.y;
  const size_t ob = (((size_t)(b * 5 + cc) * PR_ + yp) * PR_) * 32;

  if (yp == 0 || yp == PR_ - 1) {                 // halo row: all zeros
    u32x4 z = {0, 0, 0, 0};
    for (int idx = tid; idx < PR_ * 4; idx += 256) {
      *(u32x4*)(cH + ob + (size_t)idx * 8) = z;
      *(u32x4*)(cL + ob + (size_t)idx * 8) = z;
    }
    return;
  }
  const int y = yp - 1;
  __shared__ float t[32][PR_];

  for (int idx = tid; idx < 32 * 192; idx += 256) {
    const int ci = idx / 192, px = idx % 192;
    const int c = cc * 32 + ci;
    t[ci][px + 1] = (c < 131) ? cond[(((size_t)b * 131 + c) * H_ + y) * W_ + px] : 0.f;
  }
  if (tid < 32) { t[tid][0] = 0.f; t[tid][PR_ - 1] = 0.f; }
  __syncthreads();
  for (int idx = tid; idx < PR_ * 4; idx += 256) {   // (px, 8ch-seg)
    const int px = idx >> 2, sg = idx & 3;
    u32x4 vh, vl;
    #pragma unroll
    for (int q = 0; q < 4; ++q) {
      const int c0 = sg * 8 + q * 2;
      const float va = t[c0][px], vb = t[c0 + 1][px];
      const unsigned short ha = f2bf(va), hb = f2bf(vb);
      vh[q] = (unsigned)ha | ((unsigned)hb << 16);
      const unsigned short la = f2bf(va - bf2f(ha)), lb = f2bf(vb - bf2f(hb));
      vl[q] = (unsigned)la | ((unsigned)lb << 16);
    }
    *(u32x4*)(cH + ob + (size_t)idx * 8) = vh;
    *(u32x4*)(cL + ob + (size_t)idx * 8) = vl;
  }
}

// ---------------------------------------------------------------------------
// zero halo of chunked padded NHWC-32 hi/lo pair ([b][2][194][194][32])
// ---------------------------------------------------------------------------
__global__ __launch_bounds__(256) void halo_zero(unsigned short* __restrict__ H,
                                                 unsigned short* __restrict__ L)
{
  const int idx = blockIdx.x * 256 + threadIdx.x;
  if (idx >= B_ * 2 * PR_ * PR_) return;
  const int r  = idx % (PR_ * PR_);
  const int yp = r / PR_, xp = r % PR_;
  if (yp == 0 || yp == PR_ - 1 || xp == 0 || xp == PR_ - 1) {
    u32x4 z = {0, 0, 0, 0};
    const size_t base = (size_t)idx * 32;
    #pragma unroll
    for (int j = 0; j < 4; ++j) {
      *(u32x4*)(H + base + j * 8) = z;
      *(u32x4*)(L + base + j * 8) = z;
    }
  }
}

// ---------------------------------------------------------------------------
// MFMA 3x3 conv on chunked padded NHWC-32 hi/lo bf16. Tile 64px x (NW*16) oc.
// 3-term hi/lo MFMA: W_h*x_h + W_l*x_h + W_h*x_l (fp32 acc).
// All 3 ky-rows staged per cc phase (1 barrier pair per cc, 108 MFMA between).
// 1D grid, XCD-chunked remap: each XCD owns contiguous rows -> halo L2 reuse.
// EPI 0: lrelu -> hi/lo split -> chunked padded store. EPI 1: conv4 epilogue.
// CW = weight c-stride (160 for conv1, 64 otherwise).
// ---------------------------------------------------------------------------
template<int NCC, int NW, int EPI, int CW>
__global__ __launch_bounds__(NW * 64) void conv_mfma(
    const unsigned short* __restrict__ inH, const unsigned short* __restrict__ inL,
    const unsigned short* __restrict__ WH, const unsigned short* __restrict__ WL,
    const float* __restrict__ bias, const float* __restrict__ flow,
    unsigned short* __restrict__ outH, unsigned short* __restrict__ outL,
    float* __restrict__ om)
{
  constexpr int OPAD = NW * 16;
  const int tid = threadIdx.x;
  const int lane = tid & 63, wv = tid >> 6;
  const int g = lane >> 4, l16 = lane & 15;
  // XCD-chunked bijective remap (1152 blocks, 1152 % 8 == 0)
  const int nwg8 = (3 * 192 * B_) / 8;
  const int t = blockIdx.x;
  const int gi = (t & 7) * nwg8 + (t >> 3);
  const int p0 = (gi % 3) * 64;
  const int y  = (gi / 3) % 192;
  const int b  = gi / 576;

  // smem: staging 3 rows x (hi,lo) x 264 x 8 shorts = 25344B; epilogue reuses
  __shared__ __align__(16) unsigned short smem[3 * 4224];

  f32x4 acc[4];
  {
    float bv[4];
    #pragma unroll
    for (int r = 0; r < 4; ++r) {
      const int oc = wv * 16 + g * 4 + r;
      bv[r] = (EPI == 1 && oc >= 27) ? 0.f : bias[oc];
    }
    #pragma unroll
    for (int n = 0; n < 4; ++n) {
      acc[n][0] = bv[0]; acc[n][1] = bv[1]; acc[n][2] = bv[2]; acc[n][3] = bv[3];
    }
  }

  for (int cc = 0; cc < NCC; ++cc) {
    __syncthreads();
    // stage 3 rows x 66px x 32c hi/lo, swizzled: slot s holds cg = s ^ ((px>>1)&3)
    for (int ch = tid; ch < 792; ch += NW * 64) {
      const int row = ch / 264, c2 = ch % 264;
      const int px = c2 >> 2, s = c2 & 3;
      const int cg = s ^ ((px >> 1) & 3);
      const size_t so = ((((size_t)b * NCC + cc) * PR_ + (y + row)) * PR_ + p0 + px) * 32 + cg * 8;
      *(u32x4*)(smem + row * 4224 + c2 * 8)        = *(const u32x4*)(inH + so);
      *(u32x4*)(smem + row * 4224 + 2112 + c2 * 8) = *(const u32x4*)(inL + so);
    }
    __syncthreads();
    #pragma unroll
    for (int ky = 0; ky < 3; ++ky) {
      const unsigned short* stH = smem + ky * 4224;
      const unsigned short* stL = stH + 2112;
      #pragma unroll
      for (int kx = 0; kx < 3; ++kx) {
        const int k = ky * 3 + kx;
        const size_t wo = ((size_t)(k * OPAD + wv * 16 + l16)) * CW + cc * 32 + g * 8;
        const bf16x8 aH = *(const bf16x8*)(WH + wo);
        const bf16x8 aL = *(const bf16x8*)(WL + wo);
        #pragma unroll
        for (int n = 0; n < 4; ++n) {
          const int pxt = n * 16 + l16 + kx;
          const int bo = pxt * 32 + ((g ^ ((pxt >> 1) & 3)) * 8);
          const bf16x8 bH = *(const bf16x8*)(stH + bo);
          const bf16x8 bL = *(const bf16x8*)(stL + bo);
          acc[n] = __builtin_amdgcn_mfma_f32_16x16x32_bf16(aH, bH, acc[n], 0, 0, 0);
          acc[n] = __builtin_amdgcn_mfma_f32_16x16x32_bf16(aL, bH, acc[n], 0, 0, 0);
          acc[n] = __builtin_amdgcn_mfma_f32_16x16x32_bf16(aH, bL, acc[n], 0, 0, 0);
        }
      }
    }
  }

  if (EPI == 0) {
    // lrelu -> hi/lo split -> LDS transpose -> coalesced chunked store
    __syncthreads();
    unsigned short* eH = smem;
    unsigned short* eL = smem + 64 * 72;
    #pragma unroll
    for (int n = 0; n < 4; ++n) {
      const int px = n * 16 + l16;
      #pragma unroll
      for (int r = 0; r < 4; ++r) {
        const int c = wv * 16 + g * 4 + r;
        float v = acc[n][r];
        v = (v >= 0.f) ? v : 0.1f * v;
        const unsigned short h = f2bf(v);
        eH[px * 72 + c] = h;
        eL[px * 72 + c] = f2bf(v - bf2f(h));
      }
    }
    __syncthreads();
    const int px = tid >> 2, cq = tid & 3;
    const int cc = cq >> 1;
    const size_t ob = ((((size_t)b * 2 + cc) * PR_ + (y + 1)) * PR_ + (p0 + px + 1)) * 32
                    + (cq & 1) * 16;
    const u32x4 h0 = *(const u32x4*)(eH + px * 72 + cq * 16);
    const u32x4 h1 = *(const u32x4*)(eH + px * 72 + cq * 16 + 8);
    const u32x4 l0 = *(const u32x4*)(eL + px * 72 + cq * 16);
    const u32x4 l1 = *(const u32x4*)(eL + px * 72 + cq * 16 + 8);
    *(u32x4*)(outH + ob)     = h0;
    *(u32x4*)(outH + ob + 8) = h1;
    *(u32x4*)(outL + ob)     = l0;
    *(u32x4*)(outL + ob + 8) = l1;
  } else {
    // conv4: offsets (10*tanh + flow_yx) / sigmoid mask -> fp32 NCHW om
    #pragma unroll
    for (int n = 0; n < 4; ++n) {
      const int px = p0 + n * 16 + l16;
      #pragma unroll
      for (int r = 0; r < 4; ++r) {
        const int oc = wv * 16 + g * 4 + r;
        if (oc >= 27) continue;
        float v = acc[n][r];
        if (oc < 18) {
          const float f = flow[(((size_t)b * 2 + ((oc & 1) ? 0 : 1)) * H_ + y) * W_ + px];
          v = 10.f * tanhf(v) + f;
        } else {
          v = 1.f / (1.f + expf(-v));
        }
        om[((size_t)(b * 27 + oc) * HW_) + (size_t)y * W_ + px] = v;
      }
    }
  }
}

// ---------------------------------------------------------------------------
// deform weight (O=64,C=64,3,3) fp32 -> W2[k][o][c] bf16
// ---------------------------------------------------------------------------
__global__ __launch_bounds__(256) void prep_w2(const float* __restrict__ w,
                                               unsigned short* __restrict__ W2)
{
  const int i = blockIdx.x * 256 + threadIdx.x;
  if (i < 64 * 64 * 9) {
    const int o = i / 576;
    const int rem = i % 576;
    const int c = rem / 9;
    const int k = rem % 9;
    W2[((size_t)k * 64 + o) * 64 + c] = f2bf(w[i]);
  }
}

// ---------------------------------------------------------------------------
// x NCHW fp32 -> NHWC bf16: xTb[b][p][c]
// ---------------------------------------------------------------------------
__global__ __launch_bounds__(256) void transpose_x(const float* __restrict__ x,
                                                   unsigned short* __restrict__ xTb)
{
  const int tid = threadIdx.x;
  const int lane = tid & 63, wv = tid >> 6;
  const int blocksPerB = HW_ / 64;
  const int b = blockIdx.x / blocksPerB;
  const int p0 = (blockIdx.x % blocksPerB) * 64;

  __shared__ float t[64][65];
  const float* xb = x + (size_t)b * C_ * HW_;
  #pragma unroll
  for (int j = 0; j < 16; ++j) {
    const int c = wv * 16 + j;
    t[c][lane] = xb[(size_t)c * HW_ + p0 + lane];
  }
  __syncthreads();
  unsigned short* xo = xTb + ((size_t)b * HW_ + p0) * 64;
  const int c4 = (tid & 15) * 4;
  const int pb = tid >> 4;
  #pragma unroll
  for (int pp = 0; pp < 4; ++pp) {
    const int p = pb + 16 * pp;
    ushort4 v = { f2bf(t[c4][p]), f2bf(t[c4+1][p]), f2bf(t[c4+2][p]), f2bf(t[c4+3][p]) };
    *(ushort4*)(xo + (size_t)p * 64 + c4) = v;
  }
}

// ---------------------------------------------------------------------------
// Deformable conv, bf16 MFMA (unchanged — verified)
// ---------------------------------------------------------------------------
__global__ __launch_bounds__(256) void deform_k(
    const unsigned short* __restrict__ xTb, const float* __restrict__ om,
    const unsigned short* __restrict__ W2, const float* __restrict__ bias,
    float* __restrict__ out)
{
  const int tid = threadIdx.x;
  const int lane = tid & 63, wv = tid >> 6;
  const int g = lane >> 4;
  const int l16 = lane & 15;
  const int blocksPerB = HW_ / 64;
  const int b = blockIdx.x / blocksPerB;
  const int rem = blockIdx.x % blocksPerB;
  const int h = (rem * 64) / W_;
  const int w0 = (rem * 64) % W_;

  __shared__ int   ci[4][9][64];
  __shared__ float cw[4][9][64];
  __shared__ __align__(16) unsigned short valk[64 * 64];

  for (int idx = tid; idx < 9 * 64; idx += 256) {
    const int k = idx >> 6, p = idx & 63;
    const size_t base = (size_t)b * 27 * HW_ + (size_t)h * W_ + w0 + p;
    const float dy = om[base + (size_t)(2 * k) * HW_];
    const float dx = om[base + (size_t)(2 * k + 1) * HW_];
    const float m  = om[base + (size_t)(18 + k) * HW_];
    const int ky = k / 3, kx = k - ky * 3;
    const float py = dy + (float)(h - 1 + ky);
    const float px = dx + (float)(w0 + p - 1 + kx);
    const float y0f = floorf(py), x0f = floorf(px);
    const float ly = py - y0f, lx = px - x0f;
    const int y0 = (int)y0f, x0 = (int)x0f;
    const int y1 = y0 + 1, x1 = x0 + 1;
    float w00 = (1.f - ly) * (1.f - lx), w01 = (1.f - ly) * lx;
    float w10 = ly * (1.f - lx),        w11 = ly * lx;
    if (!(y0 >= 0 && y0 < H_)) { w00 = 0.f; w01 = 0.f; }
    if (!(y1 >= 0 && y1 < H_)) { w10 = 0.f; w11 = 0.f; }
    if (!(x0 >= 0 && x0 < W_)) { w00 = 0.f; w10 = 0.f; }
    if (!(x1 >= 0 && x1 < W_)) { w01 = 0.f; w11 = 0.f; }
    const int yc0 = min(max(y0, 0), H_ - 1), yc1 = min(max(y1, 0), H_ - 1);
    const int xc0 = min(max(x0, 0), W_ - 1), xc1 = min(max(x1, 0), W_ - 1);
    ci[0][k][p] = yc0 * W_ + xc0;  cw[0][k][p] = m * w00;
    ci[1][k][p] = yc0 * W_ + xc1;  cw[1][k][p] = m * w01;
    ci[2][k][p] = yc1 * W_ + xc0;  cw[2][k][p] = m * w10;
    ci[3][k][p] = yc1 * W_ + xc1;  cw[3][k][p] = m * w11;
  }

  f32x4 acc[4];
  {
    float br[4];
    #pragma unroll
    for (int r = 0; r < 4; ++r) br[r] = bias[wv * 16 + g * 4 + r];
    #pragma unroll
    for (int n = 0; n < 4; ++n) { acc[n][0]=br[0]; acc[n][1]=br[1]; acc[n][2]=br[2]; acc[n][3]=br[3]; }
  }

  const unsigned short* xb = xTb + (size_t)b * HW_ * 64;
  __syncthreads();

  for (int k = 0; k < 9; ++k) {
    #pragma unroll
    for (int i = 0; i < 2; ++i) {
      const int it = tid + (i << 8);
      const int cg = it & 7, p = it >> 3;
      const int i00 = ci[0][k][p], i01 = ci[1][k][p];
      const int i10 = ci[2][k][p], i11 = ci[3][k][p];
      const float q00 = cw[0][k][p], q01 = cw[1][k][p];
      const float q10 = cw[2][k][p], q11 = cw[3][k][p];
      const u32x4 va = *(const u32x4*)(xb + ((size_t)i00 * 64 + cg * 8));
      const u32x4 vb = *(const u32x4*)(xb + ((size_t)i01 * 64 + cg * 8));
      const u32x4 vc = *(const u32x4*)(xb + ((size_t)i10 * 64 + cg * 8));
      const u32x4 vd = *(const u32x4*)(xb + ((size_t)i11 * 64 + cg * 8));
      u32x4 res;
      #pragma unroll
      for (int j = 0; j < 4; ++j) {
        const float lo = q00*bflo(va[j]) + q01*bflo(vb[j]) + q10*bflo(vc[j]) + q11*bflo(vd[j]);
        const float hi = q00*bfhi(va[j]) + q01*bfhi(vb[j]) + q10*bfhi(vc[j]) + q11*bfhi(vd[j]);
        res[j] = pkbf(lo, hi);
      }
      *(u32x4*)&valk[(p << 6) + ((cg ^ (p & 7)) << 3)] = res;
    }

    const unsigned short* w2t = W2 + ((size_t)k * 64 + wv * 16 + l16) * 64 + g * 8;
    const bf16x8 a0 = *(const bf16x8*)(w2t);
    const bf16x8 a1 = *(const bf16x8*)(w2t + 32);

    __syncthreads();

    #pragma unroll
    for (int n = 0; n < 4; ++n) {
      const int p = n * 16 + l16;
      const bf16x8 b0 = *(const bf16x8*)&valk[(p << 6) + (((g    ) ^ (p & 7)) << 3)];
      const bf16x8 b1 = *(const bf16x8*)&valk[(p << 6) + (((g + 4) ^ (p & 7)) << 3)];
      acc[n] = __builtin_amdgcn_mfma_f32_16x16x32_bf16(a0, b0, acc[n], 0, 0, 0);
      acc[n] = __builtin_amdgcn_mfma_f32_16x16x32_bf16(a1, b1, acc[n], 0, 0, 0);
    }
    __syncthreads();
  }

  #pragma unroll
  for (int n = 0; n < 4; ++n) {
    #pragma unroll
    for (int r = 0; r < 4; ++r) {
      const int oc = wv * 16 + g * 4 + r;
      out[((size_t)(b * C_ + oc) * HW_) + (size_t)h * W_ + w0 + n * 16 + l16] = acc[n][r];
    }
  }
}

// ---------------------------------------------------------------------------
extern "C" void kernel_launch(void* const* d_in, const int* in_sizes, int n_in,
                              void* d_out, int out_size, void* d_ws, size_t ws_size,
                              hipStream_t stream) {
  const float* x         = (const float*)d_in[0];
  const float* cond_feat = (const float*)d_in[1];
  const float* flow      = (const float*)d_in[2];
  const float* w1 = (const float*)d_in[3];  const float* b1 = (const float*)d_in[4];
  const float* w2 = (const float*)d_in[5];  const float* b2 = (const float*)d_in[6];
  const float* w3 = (const float*)d_in[7];  const float* b3 = (const float*)d_in[8];
  const float* w4 = (const float*)d_in[9];  const float* b4 = (const float*)d_in[10];
  const float* wgt = (const float*)d_in[11]; const float* bias = (const float*)d_in[12];

  float* outp = (float*)d_out;

  // workspace layout (256B-aligned chunks)
  char* wsp = (char*)d_ws;
  size_t off = 0;
  auto alloc = [&](size_t bytes) { char* p = wsp + off; off += (bytes + 255) & ~(size_t)255; return p; };
  const size_t padHW = (size_t)PR_ * PR_;                       // 37636
  unsigned short* condH = (unsigned short*)alloc(B_ * 5 * padHW * 32 * 2);
  unsigned short* condL = (unsigned short*)alloc(B_ * 5 * padHW * 32 * 2);
  unsigned short* hA_H  = (unsigned short*)alloc(B_ * 2 * padHW * 32 * 2);
  unsigned short* hA_L  = (unsigned short*)alloc(B_ * 2 * padHW * 32 * 2);
  unsigned short* hB_H  = (unsigned short*)alloc(B_ * 2 * padHW * 32 * 2);
  unsigned short* hB_L  = (unsigned short*)alloc(B_ * 2 * padHW * 32 * 2);
  float*          om    = (float*)alloc((size_t)B_ * 27 * HW_ * 4);
  unsigned short* xTb   = (unsigned short*)alloc((size_t)B_ * HW_ * 64 * 2);
  unsigned short* W2d   = (unsigned short*)alloc(9 * 64 * 64 * 2);
  unsigned short* W1H   = (unsigned short*)alloc(9 * 64 * 160 * 2);
  unsigned short* W1L   = (unsigned short*)alloc(9 * 64 * 160 * 2);
  unsigned short* W2H   = (unsigned short*)alloc(9 * 64 * 64 * 2);
  unsigned short* W2L   = (unsigned short*)alloc(9 * 64 * 64 * 2);
  unsigned short* W3H   = (unsigned short*)alloc(9 * 64 * 64 * 2);
  unsigned short* W3L   = (unsigned short*)alloc(9 * 64 * 64 * 2);
  unsigned short* W4H   = (unsigned short*)alloc(9 * 32 * 64 * 2);
  unsigned short* W4L   = (unsigned short*)alloc(9 * 32 * 64 * 2);

  // weight prep
  prep_cw<64, 131, 64, 160><<<(9*64*160 + 255)/256, 256, 0, stream>>>(w1, W1H, W1L);
  prep_cw<64, 64, 64, 64><<<(9*64*64 + 255)/256, 256, 0, stream>>>(w2, W2H, W2L);
  prep_cw<64, 64, 64, 64><<<(9*64*64 + 255)/256, 256, 0, stream>>>(w3, W3H, W3L);
  prep_cw<27, 64, 32, 64><<<(9*32*64 + 255)/256, 256, 0, stream>>>(w4, W4H, W4L);
  prep_w2<<<144, 256, 0, stream>>>(wgt, W2d);

  // input prep
  transpose_cond<<<dim3(B_ * PR_, 5), 256, 0, stream>>>(cond_feat, condH, condL);
  halo_zero<<<(B_ * 2 * PR_ * PR_ + 255)/256, 256, 0, stream>>>(hA_H, hA_L);
  halo_zero<<<(B_ * 2 * PR_ * PR_ + 255)/256, 256, 0, stream>>>(hB_H, hB_L);
  transpose_x<<<(B_ * HW_)/64, 256, 0, stream>>>(x, xTb);

  // conv chain (MFMA), 1D grid with in-kernel XCD-chunked remap
  const int nwg = 3 * 192 * B_;   // 1152
  conv_mfma<5, 4, 0, 160><<<nwg, 256, 0, stream>>>(condH, condL, W1H, W1L, b1, nullptr, hA_H, hA_L, nullptr);
  conv_mfma<2, 4, 0, 64><<<nwg, 256, 0, stream>>>(hA_H, hA_L, W2H, W2L, b2, nullptr, hB_H, hB_L, nullptr);
  conv_mfma<2, 4, 0, 64><<<nwg, 256, 0, stream>>>(hB_H, hB_L, W3H, W3L, b3, nullptr, hA_H, hA_L, nullptr);
  conv_mfma<2, 2, 1, 64><<<nwg, 128, 0, stream>>>(hA_H, hA_L, W4H, W4L, b4, flow, nullptr, nullptr, om);

  // deformable conv
  deform_k<<<(B_ * HW_)/64, 256, 0, stream>>>(xTb, om, W2d, bias, outp);
}